// Round 3
// baseline (407.681 us; speedup 1.0000x reference)
//
#include <hip/hip_runtime.h>

typedef __bf16 bf16;
typedef __bf16 bf16x8 __attribute__((ext_vector_type(8)));
typedef float  f32x4  __attribute__((ext_vector_type(4)));

#define MFMA(a, b, c) __builtin_amdgcn_mfma_f32_16x16x32_bf16((a), (b), (c), 0, 0, 0)

// ---------------- f32 -> bf16 bulk convert (8 elems/thread)
__global__ __launch_bounds__(256)
void f2b_k(const float* __restrict__ in, bf16* __restrict__ out, int n8)
{
  int i = blockIdx.x * 256 + threadIdx.x;
  if (i >= n8) return;
  f32x4 a = *(const f32x4*)(in + (size_t)i * 8);
  f32x4 b = *(const f32x4*)(in + (size_t)i * 8 + 4);
  bf16x8 o;
#pragma unroll
  for (int j = 0; j < 4; ++j) { o[j] = (bf16)a[j]; o[4 + j] = (bf16)b[j]; }
  *(bf16x8*)(out + (size_t)i * 8) = o;
}

// shifted-window token t = w*256+n  ->  natural token index (b*4096 + gh*64 + gw)
__device__ __forceinline__ int row_map(int t) {
  int w = t >> 8, n = t & 255;
  int b = w >> 4, wi = w & 15;
  int gh = (((wi >> 2) << 4) + (n >> 4) + 8) & 63;
  int gw = (((wi & 3) << 4) + (n & 15) + 8) & 63;
  return (b << 12) + (gh << 6) + gw;
}

// ---------------- GEMM: C[M][N] = A[M][K] @ W[N][K]^T (reg-staged LDS; 128x128 tile)
// MODE 0: QKV  (A row-gather via row_map, bias=concat(qb,0,vb))
// MODE 1: PROJ (bias, out rows scattered via row_map)
// MODE 2: FC1  (bias + exact GELU)
// MODE 3: FC2 first half  (bias, plain write)
// MODE 4: FC2 second half (no bias, accumulate into existing out)
template<int MODE>
__global__ __launch_bounds__(256)
void gemm_k(const bf16* __restrict__ A, const bf16* __restrict__ W,
            const float* __restrict__ b0, const float* __restrict__ b1,
            bf16* __restrict__ outb, int M, int N, int K, int ldw)
{
  __shared__ __align__(16) bf16 As[128 * 32];
  __shared__ __align__(16) bf16 Bs[128 * 32];
  const int tid  = threadIdx.x;
  const int lane = tid & 63;
  const int wave = tid >> 6;
  const int wr = (wave >> 1) * 64, wc = (wave & 1) * 64;
  const int m0 = blockIdx.x * 128, n0 = blockIdx.y * 128;
  const int fr = lane & 15, fq = lane >> 4;

  f32x4 acc[4][4] = {};

  for (int kt = 0; kt < K; kt += 32) {
    bf16x8 av[2], bv[2];
#pragma unroll
    for (int i = 0; i < 2; ++i) {
      int c = tid + i * 256;
      int row = c >> 2, kk = (c & 3) << 3;
      int grow = m0 + row;
      if (MODE == 0) grow = row_map(grow);
      av[i] = *(const bf16x8*)&A[(size_t)grow * K + kt + kk];
      bv[i] = *(const bf16x8*)&W[(size_t)(n0 + row) * ldw + kt + kk];
    }
    __syncthreads();     // previous tile's readers done
#pragma unroll
    for (int i = 0; i < 2; ++i) {
      int c = tid + i * 256;
      *(bf16x8*)&As[c * 8] = av[i];
      *(bf16x8*)&Bs[c * 8] = bv[i];
    }
    __syncthreads();     // writes visible

    bf16x8 aF[4], bF[4];
#pragma unroll
    for (int m = 0; m < 4; ++m)
      aF[m] = *(const bf16x8*)&As[(wr + m * 16 + fr) * 32 + fq * 8];
#pragma unroll
    for (int n = 0; n < 4; ++n)
      bF[n] = *(const bf16x8*)&Bs[(wc + n * 16 + fr) * 32 + fq * 8];
#pragma unroll
    for (int m = 0; m < 4; ++m)
#pragma unroll
      for (int n = 0; n < 4; ++n)
        acc[m][n] = MFMA(aF[m], bF[n], acc[m][n]);
  }

#pragma unroll
  for (int m = 0; m < 4; ++m) {
#pragma unroll
    for (int n = 0; n < 4; ++n) {
      int colb = n0 + wc + n * 16 + fr;
      float badd = 0.f;
      if (MODE == 0)
        badd = (colb < 512) ? b0[colb] : (colb < 1024 ? 0.f : b1[colb - 1024]);
      else if (MODE != 4)
        badd = b0[colb];
#pragma unroll
      for (int r = 0; r < 4; ++r) {
        int rowb = m0 + wr + m * 16 + fq * 4 + r;
        float v = acc[m][n][r] + badd;
        size_t oidx;
        if (MODE == 1) oidx = (size_t)row_map(rowb) * N + colb;
        else           oidx = (size_t)rowb * N + colb;
        if (MODE == 2) v = 0.5f * v * (1.f + erff(v * 0.70710678118654752f));
        if (MODE == 4) v += (float)outb[oidx];
        outb[oidx] = (bf16)v;
      }
    }
  }
}

// ---------------- CPB MLP: btab[q][16], q = (dr+15)*31 + (dc+15)
__device__ __forceinline__ float cpb_coord(int r) {
  float t = (float)r * (8.0f / 15.0f);
  float v = log2f(fabsf(t) + 1.0f) * (1.0f / 3.0f);
  return (t < 0.0f) ? -v : v;
}

__global__ __launch_bounds__(64)
void cpb_tbl_k(const float* __restrict__ w1, const float* __restrict__ b1,
               const float* __restrict__ w2, float* __restrict__ btab)
{
  const int q = blockIdx.x;           // 0..960
  const int lane = threadIdx.x;       // 64
  const float t0 = cpb_coord(q / 31 - 15);
  const float t1 = cpb_coord(q % 31 - 15);
  float part[16];
#pragma unroll
  for (int o = 0; o < 16; ++o) part[o] = 0.f;
  for (int jj = 0; jj < 8; ++jj) {
    int j = lane * 8 + jj;
    float hv = t0 * w1[j * 2] + t1 * w1[j * 2 + 1] + b1[j];
    hv = fmaxf(hv, 0.f);
#pragma unroll
    for (int o = 0; o < 16; ++o) part[o] += hv * w2[o * 512 + j];
  }
#pragma unroll
  for (int o = 0; o < 16; ++o) {
#pragma unroll
    for (int d = 1; d < 64; d <<= 1) part[o] += __shfl_xor(part[o], d);
  }
  if (lane == 0) {
#pragma unroll
    for (int o = 0; o < 16; ++o) btab[q * 16 + o] = part[o];
  }
}

// ---------------- attention: block = (rowblock rb, head hh, window w), 256 thr
#define KP 40     // padded stride for [*][32] tiles
#define NP 264    // padded stride for [*][256] tiles
__global__ __launch_bounds__(256)
void attn_k(const bf16* __restrict__ qkv, const float* __restrict__ btab,
            const float* __restrict__ lsc, bf16* __restrict__ attn_out)
{
  const int rb = blockIdx.x;     // 0..3 (64-row block)
  const int hh = blockIdx.y;     // 0..15
  const int w  = blockIdx.z;     // 0..63
  const int tid = threadIdx.x, lane = tid & 63, wave = tid >> 6;
  const int fr = lane & 15, fq = lane >> 4;

  __shared__ __align__(16) bf16 Qs[64 * KP];
  __shared__ __align__(16) bf16 Ks[256 * KP];
  __shared__ __align__(16) bf16 Vt[32 * NP];
  __shared__ __align__(16) bf16 Ps[64 * NP];

  const size_t base = (size_t)(w * 256) * 1536;
  { // Q rows rb*64..rb*64+63
    int row = tid >> 2, d = (tid & 3) << 3;
    *(bf16x8*)&Qs[row * KP + d] =
        *(const bf16x8*)&qkv[base + (size_t)(rb * 64 + row) * 1536 + hh * 32 + d];
  }
#pragma unroll
  for (int i = 0; i < 4; ++i) { // K 256 rows
    int c = tid + i * 256;
    int row = c >> 2, d = (c & 3) << 3;
    *(bf16x8*)&Ks[row * KP + d] =
        *(const bf16x8*)&qkv[base + (size_t)row * 1536 + 512 + hh * 32 + d];
  }
#pragma unroll
  for (int i = 0; i < 4; ++i) { // V transposed
    int c = tid + i * 256;
    int row = c >> 2, d = (c & 3) << 3;
    bf16x8 v = *(const bf16x8*)&qkv[base + (size_t)row * 1536 + 1024 + hh * 32 + d];
#pragma unroll
    for (int j = 0; j < 8; ++j) Vt[(d + j) * NP + row] = v[j];
  }
  __syncthreads();

  { // cosine-normalize K rows (one row per thread)
    int row = tid;
    float ss = 0.f;
    bf16x8 kv[4];
#pragma unroll
    for (int qd = 0; qd < 4; ++qd) {
      kv[qd] = *(const bf16x8*)&Ks[row * KP + qd * 8];
#pragma unroll
      for (int j = 0; j < 8; ++j) { float f = (float)kv[qd][j]; ss += f * f; }
    }
    float fac = 1.f / fmaxf(sqrtf(ss), 1e-12f);
#pragma unroll
    for (int qd = 0; qd < 4; ++qd) {
#pragma unroll
      for (int j = 0; j < 8; ++j) kv[qd][j] = (bf16)((float)kv[qd][j] * fac);
      *(bf16x8*)&Ks[row * KP + qd * 8] = kv[qd];
    }
  }
  if (tid < 64) { // normalize+scale Q rows
    float sc = __expf(fminf(lsc[hh], 4.6051701859880914f));
    int row = tid;
    float ss = 0.f;
    bf16x8 kv[4];
#pragma unroll
    for (int qd = 0; qd < 4; ++qd) {
      kv[qd] = *(const bf16x8*)&Qs[row * KP + qd * 8];
#pragma unroll
      for (int j = 0; j < 8; ++j) { float f = (float)kv[qd][j]; ss += f * f; }
    }
    float fac = sc / fmaxf(sqrtf(ss), 1e-12f);
#pragma unroll
    for (int qd = 0; qd < 4; ++qd) {
#pragma unroll
      for (int j = 0; j < 8; ++j) kv[qd][j] = (bf16)((float)kv[qd][j] * fac);
      *(bf16x8*)&Qs[row * KP + qd * 8] = kv[qd];
    }
  }
  __syncthreads();

  // S = Q(16x32) @ K^T per wave (16 rows x 256 cols)
  const int r0 = wave * 16;
  const f32x4 zero = {0.f, 0.f, 0.f, 0.f};
  bf16x8 aQ = *(const bf16x8*)&Qs[(r0 + fr) * KP + fq * 8];
  f32x4 s[16];
#pragma unroll
  for (int nt = 0; nt < 16; ++nt) {
    bf16x8 bK = *(const bf16x8*)&Ks[(nt * 16 + fr) * KP + fq * 8];
    s[nt] = MFMA(aQ, bK, zero);
  }

  // CPB bias (from 961x16 table) + shifted-window mask + softmax
  const int wh = (w >> 2) & 3, ww = w & 3;
  float rs[4];
#pragma unroll
  for (int r = 0; r < 4; ++r) {
    int ni = rb * 64 + r0 + fq * 4 + r;        // query token in window
    int ri = ni >> 4, ci = ni & 15;
    int rgi = (wh == 3) ? (ri < 8 ? 1 : 2) : 0;
    int cgi = (ww == 3) ? (ci < 8 ? 1 : 2) : 0;
    float mx = -1e30f;
#pragma unroll
    for (int nt = 0; nt < 16; ++nt) {
      int nj = nt * 16 + fr;
      int rj = nj >> 4, cj = nj & 15;
      int rgj = (wh == 3) ? (rj < 8 ? 1 : 2) : 0;
      int cgj = (ww == 3) ? (cj < 8 ? 1 : 2) : 0;
      int q = (ri - rj + 15) * 31 + (ci - cj + 15);
      float bval = btab[q * 16 + hh];
      float v = s[nt][r] + 16.f / (1.f + __expf(-bval));
      if (rgi != rgj || cgi != cgj) v -= 100.f;
      s[nt][r] = v;
      mx = fmaxf(mx, v);
    }
    mx = fmaxf(mx, __shfl_xor(mx, 1)); mx = fmaxf(mx, __shfl_xor(mx, 2));
    mx = fmaxf(mx, __shfl_xor(mx, 4)); mx = fmaxf(mx, __shfl_xor(mx, 8));
    float sum = 0.f;
#pragma unroll
    for (int nt = 0; nt < 16; ++nt) {
      float p = __expf(s[nt][r] - mx);
      s[nt][r] = p;
      sum += p;
    }
    sum += __shfl_xor(sum, 1); sum += __shfl_xor(sum, 2);
    sum += __shfl_xor(sum, 4); sum += __shfl_xor(sum, 8);
    rs[r] = sum;
  }

  // P -> LDS (bf16, unnormalized; divide after PV)
#pragma unroll
  for (int nt = 0; nt < 16; ++nt)
#pragma unroll
    for (int r = 0; r < 4; ++r)
      Ps[(r0 + fq * 4 + r) * NP + nt * 16 + fr] = (bf16)s[nt][r];
  __syncthreads();

  // O = P(16x256) @ V(256x32)
  f32x4 o[2] = {};
#pragma unroll
  for (int ks = 0; ks < 8; ++ks) {
    bf16x8 aP = *(const bf16x8*)&Ps[(r0 + fr) * NP + ks * 32 + fq * 8];
#pragma unroll
    for (int n2 = 0; n2 < 2; ++n2) {
      bf16x8 bV = *(const bf16x8*)&Vt[(n2 * 16 + fr) * NP + ks * 32 + fq * 8];
      o[n2] = MFMA(aP, bV, o[n2]);
    }
  }
#pragma unroll
  for (int n2 = 0; n2 < 2; ++n2)
#pragma unroll
    for (int r = 0; r < 4; ++r) {
      int ni = rb * 64 + r0 + fq * 4 + r;
      attn_out[((size_t)(w * 256 + ni)) * 512 + hh * 32 + n2 * 16 + fr] =
          (bf16)(o[n2][r] / rs[r]);
    }
}

// ---------------- LayerNorm + residual: out = res + LN(vin)
// MODE 0: vin bf16, res float, out bf16   (x1 = x + LN(proj))
// MODE 1: vin bf16, res bf16, out float   (final: x1 + LN(m) -> d_out fp32)
template<int MODE>
__global__ __launch_bounds__(256)
void ln_res_k(const bf16* __restrict__ vin, const void* __restrict__ res,
              const float* __restrict__ gam, const float* __restrict__ bet,
              bf16* __restrict__ outb, float* __restrict__ outf)
{
  const int row = blockIdx.x * 4 + (threadIdx.x >> 6);
  const int lane = threadIdx.x & 63;
  const size_t base = (size_t)row * 512 + lane * 8;
  bf16x8 inv = *(const bf16x8*)(vin + base);
  float v[8];
#pragma unroll
  for (int j = 0; j < 8; ++j) v[j] = (float)inv[j];
  float s = 0.f, s2 = 0.f;
#pragma unroll
  for (int j = 0; j < 8; ++j) { s += v[j]; s2 += v[j] * v[j]; }
#pragma unroll
  for (int d = 1; d < 64; d <<= 1) { s += __shfl_xor(s, d); s2 += __shfl_xor(s2, d); }
  float mean = s * (1.f / 512.f);
  float var = s2 * (1.f / 512.f) - mean * mean;
  float rstd = rsqrtf(var + 1e-5f);

  float rv[8];
  if (MODE == 0) {
    f32x4 ra = *(const f32x4*)((const float*)res + base);
    f32x4 rb = *(const f32x4*)((const float*)res + base + 4);
#pragma unroll
    for (int j = 0; j < 4; ++j) { rv[j] = ra[j]; rv[4 + j] = rb[j]; }
  } else {
    bf16x8 r8 = *(const bf16x8*)((const bf16*)res + base);
#pragma unroll
    for (int j = 0; j < 8; ++j) rv[j] = (float)r8[j];
  }
  f32x4 g1 = *(const f32x4*)(gam + lane * 8);
  f32x4 g2 = *(const f32x4*)(gam + lane * 8 + 4);
  f32x4 b1 = *(const f32x4*)(bet + lane * 8);
  f32x4 b2 = *(const f32x4*)(bet + lane * 8 + 4);

  bf16x8 ob;
  f32x4 o1, o2;
#pragma unroll
  for (int j = 0; j < 8; ++j) {
    float g = (j < 4) ? g1[j] : g2[j - 4];
    float b = (j < 4) ? b1[j] : b2[j - 4];
    float ln = (v[j] - mean) * rstd * g + b;
    float ov = rv[j] + ln;
    if (MODE == 0) ob[j] = (bf16)ov;
    else { if (j < 4) o1[j] = ov; else o2[j - 4] = ov; }
  }
  if (MODE == 0) *(bf16x8*)(outb + base) = ob;
  else { *(f32x4*)(outf + base) = o1; *(f32x4*)(outf + base + 4) = o2; }
}

// ---------------- launch
extern "C" void kernel_launch(void* const* d_in, const int* in_sizes, int n_in,
                              void* d_out, int out_size, void* d_ws, size_t ws_size,
                              hipStream_t stream) {
  const float* x    = (const float*)d_in[0];
  const float* n1g  = (const float*)d_in[3];
  const float* n1b  = (const float*)d_in[4];
  const float* qkvw = (const float*)d_in[5];
  const float* qb   = (const float*)d_in[6];
  const float* vb   = (const float*)d_in[7];
  const float* lsc  = (const float*)d_in[8];
  const float* cw1  = (const float*)d_in[9];
  const float* cb1  = (const float*)d_in[10];
  const float* cw2  = (const float*)d_in[11];
  const float* pw   = (const float*)d_in[12];
  const float* pb   = (const float*)d_in[13];
  const float* n2g  = (const float*)d_in[14];
  const float* n2b  = (const float*)d_in[15];
  const float* f1w  = (const float*)d_in[16];
  const float* f1b  = (const float*)d_in[17];
  const float* f2w  = (const float*)d_in[18];
  const float* f2b  = (const float*)d_in[19];

  // workspace layout (bytes), peak 56.7 MB:
  //   qkvw_b @0            (1,572,864)
  //   pw_b   @1,572,864    (524,288)
  //   f1w_b  @2,097,152    (2,097,152)
  //   f2w_b  @4,194,304    (2,097,152)
  //   btab   @6,291,456    (61,504)
  //   slotA  @6,356,992    (16,777,216)  xb -> attn_o -> m_buf
  //   slotB  @23,134,208   (50,331,648)  qkv_t ; then projo(16.8M) + x1b @39,911,424
  // d_out (33.5 MB float) doubles as FC1 half hidden buffer (bf16), dead
  // before the final LN writes it.
  char* ws = (char*)d_ws;
  bf16*  qkvw_b = (bf16*)(ws);
  bf16*  pw_b   = (bf16*)(ws + 1572864);
  bf16*  f1w_b  = (bf16*)(ws + 2097152);
  bf16*  f2w_b  = (bf16*)(ws + 4194304);
  float* btab   = (float*)(ws + 6291456);
  bf16*  xb     = (bf16*)(ws + 6356992);
  bf16*  attn_o = (bf16*)(ws + 6356992);
  bf16*  m_buf  = (bf16*)(ws + 6356992);
  bf16*  qkv_t  = (bf16*)(ws + 23134208);
  bf16*  projo  = (bf16*)(ws + 23134208);
  bf16*  x1b    = (bf16*)(ws + 39911424);
  bf16*  h_buf  = (bf16*)d_out;

  // convert inputs to bf16
  f2b_k<<<4096, 256, 0, stream>>>(x, xb, 1048576);
  f2b_k<<<384,  256, 0, stream>>>(qkvw, qkvw_b, 98304);
  f2b_k<<<128,  256, 0, stream>>>(pw, pw_b, 32768);
  f2b_k<<<512,  256, 0, stream>>>(f1w, f1w_b, 131072);
  f2b_k<<<512,  256, 0, stream>>>(f2w, f2w_b, 131072);
  cpb_tbl_k<<<961, 64, 0, stream>>>(cw1, cb1, cw2, btab);

  gemm_k<0><<<dim3(128, 12), 256, 0, stream>>>(xb, qkvw_b, qb, vb, qkv_t, 16384, 1536, 512, 512);
  attn_k<<<dim3(4, 16, 64), 256, 0, stream>>>(qkv_t, btab, lsc, attn_o);
  gemm_k<1><<<dim3(128, 4), 256, 0, stream>>>(attn_o, pw_b, pb, nullptr, projo, 16384, 512, 512, 512);
  ln_res_k<0><<<4096, 256, 0, stream>>>(projo, x, n1g, n1b, x1b, nullptr);
  // FC1/FC2 split over hidden halves (h in d_out region, 33.5 MB)
  gemm_k<2><<<dim3(128, 8), 256, 0, stream>>>(x1b, f1w_b, f1b, nullptr, h_buf, 16384, 1024, 512, 512);
  gemm_k<3><<<dim3(128, 4), 256, 0, stream>>>(h_buf, f2w_b, f2b, nullptr, m_buf, 16384, 512, 1024, 2048);
  gemm_k<2><<<dim3(128, 8), 256, 0, stream>>>(x1b, f1w_b + 1024 * 512, f1b + 1024, nullptr, h_buf, 16384, 1024, 512, 512);
  gemm_k<4><<<dim3(128, 4), 256, 0, stream>>>(h_buf, f2w_b + 1024, nullptr, nullptr, m_buf, 16384, 512, 1024, 2048);
  ln_res_k<1><<<4096, 256, 0, stream>>>(m_buf, x1b, n2g, n2b, nullptr, (float*)d_out);
}

// Round 4
// 334.582 us; speedup vs baseline: 1.2185x; 1.2185x over previous
//
#include <hip/hip_runtime.h>

typedef __bf16 bf16;
typedef __bf16 bf16x8 __attribute__((ext_vector_type(8)));
typedef float  f32x4  __attribute__((ext_vector_type(4)));

#define MFMA(a, b, c) __builtin_amdgcn_mfma_f32_16x16x32_bf16((a), (b), (c), 0, 0, 0)

__device__ __forceinline__ void gload16(const bf16* g, bf16* l) {
  __builtin_amdgcn_global_load_lds(
      (const __attribute__((address_space(1))) unsigned int*)g,
      (__attribute__((address_space(3))) unsigned int*)l, 16, 0, 0);
}

// ---------------- f32 -> bf16 bulk convert (8 elems/thread)
__global__ __launch_bounds__(256)
void f2b_k(const float* __restrict__ in, bf16* __restrict__ out, int n8)
{
  int i = blockIdx.x * 256 + threadIdx.x;
  if (i >= n8) return;
  f32x4 a = *(const f32x4*)(in + (size_t)i * 8);
  f32x4 b = *(const f32x4*)(in + (size_t)i * 8 + 4);
  bf16x8 o;
#pragma unroll
  for (int j = 0; j < 4; ++j) { o[j] = (bf16)a[j]; o[4 + j] = (bf16)b[j]; }
  *(bf16x8*)(out + (size_t)i * 8) = o;
}

// shifted-window token t = w*256+n  ->  natural token index (b*4096 + gh*64 + gw)
__device__ __forceinline__ int row_map(int t) {
  int w = t >> 8, n = t & 255;
  int b = w >> 4, wi = w & 15;
  int gh = (((wi >> 2) << 4) + (n >> 4) + 8) & 63;
  int gw = (((wi & 3) << 4) + (n & 15) + 8) & 63;
  return (b << 12) + (gh << 6) + gw;
}

// ---------------- GEMM: C[M][N] = A[M][K] @ W[N][K]^T (global_load_lds staging)
// MODE 0: QKV  (A row-gather via row_map, bias=concat(qb,0,vb))
// MODE 1: PROJ (bias, out rows scattered via row_map)
// MODE 2: FC1  (bias + exact GELU)
// MODE 3: FC2 first half  (bias, plain write)
// MODE 4: FC2 second half (no bias, accumulate into existing out)
template<int MODE>
__global__ __launch_bounds__(256)
void gemm_k(const bf16* __restrict__ A, const bf16* __restrict__ W,
            const float* __restrict__ b0, const float* __restrict__ b1,
            bf16* __restrict__ outb, int M, int N, int K, int ldw)
{
  __shared__ __align__(16) bf16 As[128 * 32];
  __shared__ __align__(16) bf16 Bs[128 * 32];
  const int tid  = threadIdx.x;
  const int lane = tid & 63;
  const int wave = tid >> 6;
  const int wr = (wave >> 1) * 64, wc = (wave & 1) * 64;
  const int m0 = blockIdx.x * 128, n0 = blockIdx.y * 128;
  const int fr = lane & 15, fq = lane >> 4;

  f32x4 acc[4][4] = {};

  for (int kt = 0; kt < K; kt += 32) {
    __syncthreads();     // previous tile's readers done
#pragma unroll
    for (int i = 0; i < 2; ++i) {
      int c = tid + i * 256;
      int row = c >> 2, kk = (c & 3) << 3;
      int grow = m0 + row;
      if (MODE == 0) grow = row_map(grow);
      gload16(A + (size_t)grow * K + kt + kk, &As[c * 8]);
      gload16(W + (size_t)(n0 + row) * ldw + kt + kk, &Bs[c * 8]);
    }
    __syncthreads();     // vmcnt(0) drain -> LDS writes visible

    bf16x8 aF[4], bF[4];
#pragma unroll
    for (int m = 0; m < 4; ++m)
      aF[m] = *(const bf16x8*)&As[(wr + m * 16 + fr) * 32 + fq * 8];
#pragma unroll
    for (int n = 0; n < 4; ++n)
      bF[n] = *(const bf16x8*)&Bs[(wc + n * 16 + fr) * 32 + fq * 8];
#pragma unroll
    for (int m = 0; m < 4; ++m)
#pragma unroll
      for (int n = 0; n < 4; ++n)
        acc[m][n] = MFMA(aF[m], bF[n], acc[m][n]);
  }

#pragma unroll
  for (int m = 0; m < 4; ++m) {
#pragma unroll
    for (int n = 0; n < 4; ++n) {
      int colb = n0 + wc + n * 16 + fr;
      float badd = 0.f;
      if (MODE == 0)
        badd = (colb < 512) ? b0[colb] : (colb < 1024 ? 0.f : b1[colb - 1024]);
      else if (MODE != 4)
        badd = b0[colb];
#pragma unroll
      for (int r = 0; r < 4; ++r) {
        int rowb = m0 + wr + m * 16 + fq * 4 + r;
        float v = acc[m][n][r] + badd;
        size_t oidx;
        if (MODE == 1) oidx = (size_t)row_map(rowb) * N + colb;
        else           oidx = (size_t)rowb * N + colb;
        if (MODE == 2) v = 0.5f * v * (1.f + erff(v * 0.70710678118654752f));
        if (MODE == 4) v += (float)outb[oidx];
        outb[oidx] = (bf16)v;
      }
    }
  }
}

// ---------------- CPB MLP: btab[q][16], q = (dr+15)*31 + (dc+15)
__device__ __forceinline__ float cpb_coord(int r) {
  float t = (float)r * (8.0f / 15.0f);
  float v = log2f(fabsf(t) + 1.0f) * (1.0f / 3.0f);
  return (t < 0.0f) ? -v : v;
}

__global__ __launch_bounds__(64)
void cpb_tbl_k(const float* __restrict__ w1, const float* __restrict__ b1,
               const float* __restrict__ w2, float* __restrict__ btab)
{
  const int q = blockIdx.x;           // 0..960
  const int lane = threadIdx.x;       // 64
  const float t0 = cpb_coord(q / 31 - 15);
  const float t1 = cpb_coord(q % 31 - 15);
  float part[16];
#pragma unroll
  for (int o = 0; o < 16; ++o) part[o] = 0.f;
  for (int jj = 0; jj < 8; ++jj) {
    int j = lane * 8 + jj;
    float hv = t0 * w1[j * 2] + t1 * w1[j * 2 + 1] + b1[j];
    hv = fmaxf(hv, 0.f);
#pragma unroll
    for (int o = 0; o < 16; ++o) part[o] += hv * w2[o * 512 + j];
  }
#pragma unroll
  for (int o = 0; o < 16; ++o) {
#pragma unroll
    for (int d = 1; d < 64; d <<= 1) part[o] += __shfl_xor(part[o], d);
  }
  if (lane == 0) {
#pragma unroll
    for (int o = 0; o < 16; ++o) btab[q * 16 + o] = part[o];
  }
}

// bias16[h][i][j] = 16*sigmoid(btab[idx(i,j)][h]) - 8   (bf16; -8 is
// softmax-shift-invariant and halves the bf16 ulp)
__global__ __launch_bounds__(256)
void bias_exp_k(const float* __restrict__ btab, bf16* __restrict__ bias16)
{
  int e = blockIdx.x * 256 + threadIdx.x;      // < 131072 (8 j's per thread)
  int h = e >> 13, rem = e & 8191;
  int i = rem >> 5, jc = (rem & 31) * 8;
  bf16x8 o;
#pragma unroll
  for (int jj = 0; jj < 8; ++jj) {
    int j = jc + jj;
    int q = ((i >> 4) - (j >> 4) + 15) * 31 + ((i & 15) - (j & 15) + 15);
    float v = 16.f / (1.f + __expf(-btab[q * 16 + h])) - 8.f;
    o[jj] = (bf16)v;
  }
  *(bf16x8*)&bias16[((size_t)(h * 256 + i)) * 256 + jc] = o;
}

// ---------------- attention: block = (rowblock rb, head hh, window w), 256 thr
#define KP 40     // padded stride for [*][32] tiles
#define NP 264    // padded stride for [*][256] tiles
__global__ __launch_bounds__(256)
void attn_k(const bf16* __restrict__ qkv, const bf16* __restrict__ bias16,
            const float* __restrict__ lsc, bf16* __restrict__ attn_out)
{
  const int rb = blockIdx.x;     // 0..3 (64-row block)
  const int hh = blockIdx.y;     // 0..15
  const int w  = blockIdx.z;     // 0..63
  const int tid = threadIdx.x, lane = tid & 63, wave = tid >> 6;
  const int fr = lane & 15, fq = lane >> 4;

  __shared__ __align__(16) bf16 Qs[64 * KP];
  __shared__ __align__(16) bf16 Ks[256 * KP];
  __shared__ __align__(16) bf16 Vt[32 * NP];
  __shared__ __align__(16) bf16 Ps[64 * NP];   // bias tile, then P tile

  // stage bias slice [64][256] -> Ps (each thread later overwrites with P
  // exactly the elements it reads here; no extra barrier needed)
  {
    const bf16* bp = bias16 + ((size_t)(hh * 256 + rb * 64)) * 256;
#pragma unroll
    for (int i = 0; i < 8; ++i) {
      int c = tid + i * 256;
      int row = c >> 5, d = (c & 31) * 8;
      *(bf16x8*)&Ps[row * NP + d] = *(const bf16x8*)&bp[row * 256 + d];
    }
  }

  const size_t base = (size_t)(w * 256) * 1536;
  { // Q rows rb*64..rb*64+63
    int row = tid >> 2, d = (tid & 3) << 3;
    *(bf16x8*)&Qs[row * KP + d] =
        *(const bf16x8*)&qkv[base + (size_t)(rb * 64 + row) * 1536 + hh * 32 + d];
  }
#pragma unroll
  for (int i = 0; i < 4; ++i) { // K 256 rows
    int c = tid + i * 256;
    int row = c >> 2, d = (c & 3) << 3;
    *(bf16x8*)&Ks[row * KP + d] =
        *(const bf16x8*)&qkv[base + (size_t)row * 1536 + 512 + hh * 32 + d];
  }
#pragma unroll
  for (int i = 0; i < 4; ++i) { // V transposed
    int c = tid + i * 256;
    int row = c >> 2, d = (c & 3) << 3;
    bf16x8 v = *(const bf16x8*)&qkv[base + (size_t)row * 1536 + 1024 + hh * 32 + d];
#pragma unroll
    for (int j = 0; j < 8; ++j) Vt[(d + j) * NP + row] = v[j];
  }
  __syncthreads();

  { // cosine-normalize K rows (one row per thread)
    int row = tid;
    float ss = 0.f;
    bf16x8 kv[4];
#pragma unroll
    for (int qd = 0; qd < 4; ++qd) {
      kv[qd] = *(const bf16x8*)&Ks[row * KP + qd * 8];
#pragma unroll
      for (int j = 0; j < 8; ++j) { float f = (float)kv[qd][j]; ss += f * f; }
    }
    float fac = 1.f / fmaxf(sqrtf(ss), 1e-12f);
#pragma unroll
    for (int qd = 0; qd < 4; ++qd) {
#pragma unroll
      for (int j = 0; j < 8; ++j) kv[qd][j] = (bf16)((float)kv[qd][j] * fac);
      *(bf16x8*)&Ks[row * KP + qd * 8] = kv[qd];
    }
  }
  if (tid < 64) { // normalize+scale Q rows
    float sc = __expf(fminf(lsc[hh], 4.6051701859880914f));
    int row = tid;
    float ss = 0.f;
    bf16x8 kv[4];
#pragma unroll
    for (int qd = 0; qd < 4; ++qd) {
      kv[qd] = *(const bf16x8*)&Qs[row * KP + qd * 8];
#pragma unroll
      for (int j = 0; j < 8; ++j) { float f = (float)kv[qd][j]; ss += f * f; }
    }
    float fac = sc / fmaxf(sqrtf(ss), 1e-12f);
#pragma unroll
    for (int qd = 0; qd < 4; ++qd) {
#pragma unroll
      for (int j = 0; j < 8; ++j) kv[qd][j] = (bf16)((float)kv[qd][j] * fac);
      *(bf16x8*)&Qs[row * KP + qd * 8] = kv[qd];
    }
  }
  __syncthreads();

  // S = Q(16x32) @ K^T per wave (16 rows x 256 cols)
  const int r0 = wave * 16;
  const f32x4 zero = {0.f, 0.f, 0.f, 0.f};
  bf16x8 aQ = *(const bf16x8*)&Qs[(r0 + fr) * KP + fq * 8];
  f32x4 s[16];
#pragma unroll
  for (int nt = 0; nt < 16; ++nt) {
    bf16x8 bK = *(const bf16x8*)&Ks[(nt * 16 + fr) * KP + fq * 8];
    s[nt] = MFMA(aQ, bK, zero);
  }

  // bias (LDS) + shifted-window mask + softmax
  const int wh = (w >> 2) & 3, ww = w & 3;
  float rs[4];
#pragma unroll
  for (int r = 0; r < 4; ++r) {
    int lrow = r0 + fq * 4 + r;                // row within 64-row tile
    int ni = rb * 64 + lrow;                   // query token in window
    int ri = ni >> 4, ci = ni & 15;
    int rgi = (wh == 3) ? (ri < 8 ? 1 : 2) : 0;
    int cgi = (ww == 3) ? (ci < 8 ? 1 : 2) : 0;
    float mx = -1e30f;
#pragma unroll
    for (int nt = 0; nt < 16; ++nt) {
      int nj = nt * 16 + fr;
      int rj = nj >> 4, cj = nj & 15;
      int rgj = (wh == 3) ? (rj < 8 ? 1 : 2) : 0;
      int cgj = (ww == 3) ? (cj < 8 ? 1 : 2) : 0;
      float v = s[nt][r] + (float)Ps[lrow * NP + nj];
      if (rgi != rgj || cgi != cgj) v -= 100.f;
      s[nt][r] = v;
      mx = fmaxf(mx, v);
    }
    mx = fmaxf(mx, __shfl_xor(mx, 1)); mx = fmaxf(mx, __shfl_xor(mx, 2));
    mx = fmaxf(mx, __shfl_xor(mx, 4)); mx = fmaxf(mx, __shfl_xor(mx, 8));
    float sum = 0.f;
#pragma unroll
    for (int nt = 0; nt < 16; ++nt) {
      float p = __expf(s[nt][r] - mx);
      s[nt][r] = p;
      sum += p;
    }
    sum += __shfl_xor(sum, 1); sum += __shfl_xor(sum, 2);
    sum += __shfl_xor(sum, 4); sum += __shfl_xor(sum, 8);
    rs[r] = sum;
  }

  // P -> LDS (bf16, unnormalized; divide after PV)
#pragma unroll
  for (int nt = 0; nt < 16; ++nt)
#pragma unroll
    for (int r = 0; r < 4; ++r)
      Ps[(r0 + fq * 4 + r) * NP + nt * 16 + fr] = (bf16)s[nt][r];
  __syncthreads();

  // O = P(16x256) @ V(256x32)
  f32x4 o[2] = {};
#pragma unroll
  for (int ks = 0; ks < 8; ++ks) {
    bf16x8 aP = *(const bf16x8*)&Ps[(r0 + fr) * NP + ks * 32 + fq * 8];
#pragma unroll
    for (int n2 = 0; n2 < 2; ++n2) {
      bf16x8 bV = *(const bf16x8*)&Vt[(n2 * 16 + fr) * NP + ks * 32 + fq * 8];
      o[n2] = MFMA(aP, bV, o[n2]);
    }
  }
#pragma unroll
  for (int n2 = 0; n2 < 2; ++n2)
#pragma unroll
    for (int r = 0; r < 4; ++r) {
      int ni = rb * 64 + r0 + fq * 4 + r;
      attn_out[((size_t)(w * 256 + ni)) * 512 + hh * 32 + n2 * 16 + fr] =
          (bf16)(o[n2][r] / rs[r]);
    }
}

// ---------------- LayerNorm + residual: out = res + LN(vin)
// MODE 0: vin bf16, res float, out bf16   (x1 = x + LN(proj))
// MODE 1: vin bf16, res bf16, out float   (final: x1 + LN(m) -> d_out fp32)
template<int MODE>
__global__ __launch_bounds__(256)
void ln_res_k(const bf16* __restrict__ vin, const void* __restrict__ res,
              const float* __restrict__ gam, const float* __restrict__ bet,
              bf16* __restrict__ outb, float* __restrict__ outf)
{
  const int row = blockIdx.x * 4 + (threadIdx.x >> 6);
  const int lane = threadIdx.x & 63;
  const size_t base = (size_t)row * 512 + lane * 8;
  bf16x8 inv = *(const bf16x8*)(vin + base);
  float v[8];
#pragma unroll
  for (int j = 0; j < 8; ++j) v[j] = (float)inv[j];
  float s = 0.f, s2 = 0.f;
#pragma unroll
  for (int j = 0; j < 8; ++j) { s += v[j]; s2 += v[j] * v[j]; }
#pragma unroll
  for (int d = 1; d < 64; d <<= 1) { s += __shfl_xor(s, d); s2 += __shfl_xor(s2, d); }
  float mean = s * (1.f / 512.f);
  float var = s2 * (1.f / 512.f) - mean * mean;
  float rstd = rsqrtf(var + 1e-5f);

  float rv[8];
  if (MODE == 0) {
    f32x4 ra = *(const f32x4*)((const float*)res + base);
    f32x4 rb = *(const f32x4*)((const float*)res + base + 4);
#pragma unroll
    for (int j = 0; j < 4; ++j) { rv[j] = ra[j]; rv[4 + j] = rb[j]; }
  } else {
    bf16x8 r8 = *(const bf16x8*)((const bf16*)res + base);
#pragma unroll
    for (int j = 0; j < 8; ++j) rv[j] = (float)r8[j];
  }
  f32x4 g1 = *(const f32x4*)(gam + lane * 8);
  f32x4 g2 = *(const f32x4*)(gam + lane * 8 + 4);
  f32x4 b1 = *(const f32x4*)(bet + lane * 8);
  f32x4 b2 = *(const f32x4*)(bet + lane * 8 + 4);

  bf16x8 ob;
  f32x4 o1, o2;
#pragma unroll
  for (int j = 0; j < 8; ++j) {
    float g = (j < 4) ? g1[j] : g2[j - 4];
    float b = (j < 4) ? b1[j] : b2[j - 4];
    float ln = (v[j] - mean) * rstd * g + b;
    float ov = rv[j] + ln;
    if (MODE == 0) ob[j] = (bf16)ov;
    else { if (j < 4) o1[j] = ov; else o2[j - 4] = ov; }
  }
  if (MODE == 0) *(bf16x8*)(outb + base) = ob;
  else { *(f32x4*)(outf + base) = o1; *(f32x4*)(outf + base + 4) = o2; }
}

// ---------------- launch
extern "C" void kernel_launch(void* const* d_in, const int* in_sizes, int n_in,
                              void* d_out, int out_size, void* d_ws, size_t ws_size,
                              hipStream_t stream) {
  const float* x    = (const float*)d_in[0];
  const float* n1g  = (const float*)d_in[3];
  const float* n1b  = (const float*)d_in[4];
  const float* qkvw = (const float*)d_in[5];
  const float* qb   = (const float*)d_in[6];
  const float* vb   = (const float*)d_in[7];
  const float* lsc  = (const float*)d_in[8];
  const float* cw1  = (const float*)d_in[9];
  const float* cb1  = (const float*)d_in[10];
  const float* cw2  = (const float*)d_in[11];
  const float* pw   = (const float*)d_in[12];
  const float* pb   = (const float*)d_in[13];
  const float* n2g  = (const float*)d_in[14];
  const float* n2b  = (const float*)d_in[15];
  const float* f1w  = (const float*)d_in[16];
  const float* f1b  = (const float*)d_in[17];
  const float* f2w  = (const float*)d_in[18];
  const float* f2b  = (const float*)d_in[19];

  // workspace layout (bytes), peak 75.6 MB (round-3 proved >= 73.5 MB OK):
  //   qkvw_b @0            (1,572,864)
  //   pw_b   @1,572,864    (524,288)
  //   f1w_b  @2,097,152    (2,097,152)
  //   f2w_b  @4,194,304    (2,097,152)
  //   btab   @6,291,456    (65,536)
  //   bias16 @6,356,992    (2,097,152)
  //   slotA  @8,454,144    (16,777,216)  xb -> attn_o -> m_buf
  //   slotB  @25,231,360   qkv_t(50.3M); later projo(16.8M) + x1b @42,008,576
  // d_out (33.5 MB float) doubles as FC1 half hidden buffer (bf16).
  char* ws = (char*)d_ws;
  bf16*  qkvw_b = (bf16*)(ws);
  bf16*  pw_b   = (bf16*)(ws + 1572864);
  bf16*  f1w_b  = (bf16*)(ws + 2097152);
  bf16*  f2w_b  = (bf16*)(ws + 4194304);
  float* btab   = (float*)(ws + 6291456);
  bf16*  bias16 = (bf16*)(ws + 6356992);
  bf16*  xb     = (bf16*)(ws + 8454144);
  bf16*  attn_o = (bf16*)(ws + 8454144);
  bf16*  m_buf  = (bf16*)(ws + 8454144);
  bf16*  qkv_t  = (bf16*)(ws + 25231360);
  bf16*  projo  = (bf16*)(ws + 25231360);
  bf16*  x1b    = (bf16*)(ws + 42008576);
  bf16*  h_buf  = (bf16*)d_out;

  // convert inputs to bf16
  f2b_k<<<4096, 256, 0, stream>>>(x, xb, 1048576);
  f2b_k<<<384,  256, 0, stream>>>(qkvw, qkvw_b, 98304);
  f2b_k<<<128,  256, 0, stream>>>(pw, pw_b, 32768);
  f2b_k<<<512,  256, 0, stream>>>(f1w, f1w_b, 131072);
  f2b_k<<<512,  256, 0, stream>>>(f2w, f2w_b, 131072);
  cpb_tbl_k<<<961, 64, 0, stream>>>(cw1, cb1, cw2, btab);
  bias_exp_k<<<512, 256, 0, stream>>>(btab, bias16);

  gemm_k<0><<<dim3(128, 12), 256, 0, stream>>>(xb, qkvw_b, qb, vb, qkv_t, 16384, 1536, 512, 512);
  attn_k<<<dim3(4, 16, 64), 256, 0, stream>>>(qkv_t, bias16, lsc, attn_o);
  gemm_k<1><<<dim3(128, 4), 256, 0, stream>>>(attn_o, pw_b, pb, nullptr, projo, 16384, 512, 512, 512);
  ln_res_k<0><<<4096, 256, 0, stream>>>(projo, x, n1g, n1b, x1b, nullptr);
  // FC1/FC2 split over hidden halves (h in d_out region, 33.5 MB)
  gemm_k<2><<<dim3(128, 8), 256, 0, stream>>>(x1b, f1w_b, f1b, nullptr, h_buf, 16384, 1024, 512, 512);
  gemm_k<3><<<dim3(128, 4), 256, 0, stream>>>(h_buf, f2w_b, f2b, nullptr, m_buf, 16384, 512, 1024, 2048);
  gemm_k<2><<<dim3(128, 8), 256, 0, stream>>>(x1b, f1w_b + 1024 * 512, f1b + 1024, nullptr, h_buf, 16384, 1024, 512, 512);
  gemm_k<4><<<dim3(128, 4), 256, 0, stream>>>(h_buf, f2w_b + 1024, nullptr, nullptr, m_buf, 16384, 512, 1024, 2048);
  ln_res_k<1><<<4096, 256, 0, stream>>>(m_buf, x1b, n2g, n2b, nullptr, (float*)d_out);
}

// Round 5
// 318.959 us; speedup vs baseline: 1.2782x; 1.0490x over previous
//
#include <hip/hip_runtime.h>

typedef __bf16 bf16;
typedef __bf16 bf16x8 __attribute__((ext_vector_type(8)));
typedef float  f32x4  __attribute__((ext_vector_type(4)));

#define MFMA(a, b, c) __builtin_amdgcn_mfma_f32_16x16x32_bf16((a), (b), (c), 0, 0, 0)

__device__ __forceinline__ void gload16(const bf16* g, bf16* l) {
  __builtin_amdgcn_global_load_lds(
      (const __attribute__((address_space(1))) unsigned int*)g,
      (__attribute__((address_space(3))) unsigned int*)l, 16, 0, 0);
}

// ---------------- f32 -> bf16 bulk convert (8 elems/thread)
__global__ __launch_bounds__(256)
void f2b_k(const float* __restrict__ in, bf16* __restrict__ out, int n8)
{
  int i = blockIdx.x * 256 + threadIdx.x;
  if (i >= n8) return;
  f32x4 a = *(const f32x4*)(in + (size_t)i * 8);
  f32x4 b = *(const f32x4*)(in + (size_t)i * 8 + 4);
  bf16x8 o;
#pragma unroll
  for (int j = 0; j < 4; ++j) { o[j] = (bf16)a[j]; o[4 + j] = (bf16)b[j]; }
  *(bf16x8*)(out + (size_t)i * 8) = o;
}

// shifted-window token t = w*256+n  ->  natural token index (b*4096 + gh*64 + gw)
__device__ __forceinline__ int row_map(int t) {
  int w = t >> 8, n = t & 255;
  int b = w >> 4, wi = w & 15;
  int gh = (((wi >> 2) << 4) + (n >> 4) + 8) & 63;
  int gw = (((wi & 3) << 4) + (n & 15) + 8) & 63;
  return (b << 12) + (gh << 6) + gw;
}

// ---------------- GEMM: C[M][N] = A[M][K] @ W[N][K]^T
// double-buffered global_load_lds staging; 128x128 tile, 4 waves
// MODE 0: QKV  (A row-gather via row_map, bias=concat(qb,0,vb))
// MODE 1: PROJ (bias, out rows scattered via row_map)
// MODE 2: FC1  (bias + exact GELU)
// MODE 3: FC2 first half  (bias, plain write)
// MODE 4: FC2 second half (no bias, accumulate into existing out)
template<int MODE>
__global__ __launch_bounds__(256)
void gemm_k(const bf16* __restrict__ A, const bf16* __restrict__ W,
            const float* __restrict__ b0, const float* __restrict__ b1,
            bf16* __restrict__ outb, int M, int N, int K, int ldw)
{
  __shared__ __align__(16) bf16 As[2][128 * 32];
  __shared__ __align__(16) bf16 Bs[2][128 * 32];
  const int tid  = threadIdx.x;
  const int lane = tid & 63;
  const int wave = tid >> 6;
  const int wr = (wave >> 1) * 64, wc = (wave & 1) * 64;
  const int m0 = blockIdx.x * 128, n0 = blockIdx.y * 128;
  const int fr = lane & 15, fq = lane >> 4;

  f32x4 acc[4][4] = {};

  auto stage = [&](int b, int kt) {
#pragma unroll
    for (int i = 0; i < 2; ++i) {
      int c = tid + i * 256;
      int row = c >> 2, kk = (c & 3) << 3;
      int grow = m0 + row;
      if (MODE == 0) grow = row_map(grow);
      gload16(A + (size_t)grow * K + kt + kk, &As[b][c * 8]);
      gload16(W + (size_t)(n0 + row) * ldw + kt + kk, &Bs[b][c * 8]);
    }
  };

  const int nt = K >> 5;
  stage(0, 0);
  for (int t = 0; t < nt; ++t) {
    __syncthreads();                       // buf[t&1] loads landed; prev readers done
    if (t + 1 < nt) stage((t + 1) & 1, (t + 1) << 5);
    const int b = t & 1;
    bf16x8 aF[4], bF[4];
#pragma unroll
    for (int m = 0; m < 4; ++m)
      aF[m] = *(const bf16x8*)&As[b][(wr + m * 16 + fr) * 32 + fq * 8];
#pragma unroll
    for (int n = 0; n < 4; ++n)
      bF[n] = *(const bf16x8*)&Bs[b][(wc + n * 16 + fr) * 32 + fq * 8];
#pragma unroll
    for (int m = 0; m < 4; ++m)
#pragma unroll
      for (int n = 0; n < 4; ++n)
        acc[m][n] = MFMA(aF[m], bF[n], acc[m][n]);
  }

#pragma unroll
  for (int m = 0; m < 4; ++m) {
#pragma unroll
    for (int n = 0; n < 4; ++n) {
      int colb = n0 + wc + n * 16 + fr;
      float badd = 0.f;
      if (MODE == 0)
        badd = (colb < 512) ? b0[colb] : (colb < 1024 ? 0.f : b1[colb - 1024]);
      else if (MODE != 4)
        badd = b0[colb];
#pragma unroll
      for (int r = 0; r < 4; ++r) {
        int rowb = m0 + wr + m * 16 + fq * 4 + r;
        float v = acc[m][n][r] + badd;
        size_t oidx;
        if (MODE == 1) oidx = (size_t)row_map(rowb) * N + colb;
        else           oidx = (size_t)rowb * N + colb;
        if (MODE == 2) v = 0.5f * v * (1.f + erff(v * 0.70710678118654752f));
        if (MODE == 4) v += (float)outb[oidx];
        outb[oidx] = (bf16)v;
      }
    }
  }
}

// ---------------- CPB MLP: btab[q][16], q = (dr+15)*31 + (dc+15)
__device__ __forceinline__ float cpb_coord(int r) {
  float t = (float)r * (8.0f / 15.0f);
  float v = log2f(fabsf(t) + 1.0f) * (1.0f / 3.0f);
  return (t < 0.0f) ? -v : v;
}

__global__ __launch_bounds__(64)
void cpb_tbl_k(const float* __restrict__ w1, const float* __restrict__ b1,
               const float* __restrict__ w2, float* __restrict__ btab)
{
  const int q = blockIdx.x;           // 0..960
  const int lane = threadIdx.x;       // 64
  const float t0 = cpb_coord(q / 31 - 15);
  const float t1 = cpb_coord(q % 31 - 15);
  float part[16];
#pragma unroll
  for (int o = 0; o < 16; ++o) part[o] = 0.f;
  for (int jj = 0; jj < 8; ++jj) {
    int j = lane * 8 + jj;
    float hv = t0 * w1[j * 2] + t1 * w1[j * 2 + 1] + b1[j];
    hv = fmaxf(hv, 0.f);
#pragma unroll
    for (int o = 0; o < 16; ++o) part[o] += hv * w2[o * 512 + j];
  }
#pragma unroll
  for (int o = 0; o < 16; ++o) {
#pragma unroll
    for (int d = 1; d < 64; d <<= 1) part[o] += __shfl_xor(part[o], d);
  }
  if (lane == 0) {
#pragma unroll
    for (int o = 0; o < 16; ++o) btab[q * 16 + o] = part[o];
  }
}

// bias16[h][i][j] = 16*sigmoid(btab[idx(i,j)][h]) - 8   (bf16)
__global__ __launch_bounds__(256)
void bias_exp_k(const float* __restrict__ btab, bf16* __restrict__ bias16)
{
  int e = blockIdx.x * 256 + threadIdx.x;      // < 131072 (8 j's per thread)
  int h = e >> 13, rem = e & 8191;
  int i = rem >> 5, jc = (rem & 31) * 8;
  bf16x8 o;
#pragma unroll
  for (int jj = 0; jj < 8; ++jj) {
    int j = jc + jj;
    int q = ((i >> 4) - (j >> 4) + 15) * 31 + ((i & 15) - (j & 15) + 15);
    float v = 16.f / (1.f + __expf(-btab[q * 16 + h])) - 8.f;
    o[jj] = (bf16)v;
  }
  *(bf16x8*)&bias16[((size_t)(h * 256 + i)) * 256 + jc] = o;
}

// ---------------- attention: block = (head hh, window w), 256 thr, 4 Q-chunks
#define KP 40     // padded stride for K tile  (bank: 8fq+..., acceptable)
#define NP 260    // padded stride for [*][256] tiles (dw stride 130≡2 mod 32 -> scalar ops conflict-free)
__global__ __launch_bounds__(256)
void attn_k(const bf16* __restrict__ qkv, const bf16* __restrict__ bias16,
            const float* __restrict__ lsc, bf16* __restrict__ attn_out)
{
  const int hh = blockIdx.x;     // 0..15
  const int w  = blockIdx.y;     // 0..63
  const int tid = threadIdx.x, lane = tid & 63, wave = tid >> 6;
  const int fr = lane & 15, fq = lane >> 4;
  const int r0 = wave * 16;

  __shared__ __align__(16) bf16 Ks[256 * KP];
  __shared__ __align__(16) bf16 Vt[32 * NP];
  __shared__ __align__(16) bf16 Ps[64 * NP];   // bias tile, then P tile (per chunk)

  const size_t base = (size_t)(w * 256) * 1536;
  const float sc = __expf(fminf(lsc[hh], 4.6051701859880914f));

  // ---- stage K (cosine-normalized in-flight) and V (transposed), once
#pragma unroll
  for (int i = 0; i < 4; ++i) {
    int c = tid + i * 256;
    int row = c >> 2, d = (c & 3) << 3;     // 4 consecutive lanes share a row
    // K: load 8 elems, 4-lane row-sum of squares via shfl, scale, store
    bf16x8 kv = *(const bf16x8*)&qkv[base + (size_t)row * 1536 + 512 + hh * 32 + d];
    float ss = 0.f;
#pragma unroll
    for (int j = 0; j < 8; ++j) { float f = (float)kv[j]; ss += f * f; }
    ss += __shfl_xor(ss, 1); ss += __shfl_xor(ss, 2);
    float fac = 1.f / fmaxf(sqrtf(ss), 1e-12f);
#pragma unroll
    for (int j = 0; j < 8; ++j) kv[j] = (bf16)((float)kv[j] * fac);
    *(bf16x8*)&Ks[row * KP + d] = kv;
    // V transposed scatter
    bf16x8 v = *(const bf16x8*)&qkv[base + (size_t)row * 1536 + 1024 + hh * 32 + d];
#pragma unroll
    for (int j = 0; j < 8; ++j) Vt[(d + j) * NP + row] = v[j];
  }

  const int wh = (w >> 2) & 3, ww = w & 3;

  for (int cb = 0; cb < 4; ++cb) {
    __syncthreads();   // K/V visible (cb=0); prev chunk's Ps readers done (cb>0)

    // stage bias chunk [64][256] -> Ps
    {
      const bf16* bp = bias16 + ((size_t)(hh * 256 + cb * 64)) * 256;
#pragma unroll
      for (int i = 0; i < 8; ++i) {
        int c = tid + i * 256;
        int brow = c >> 5, bd = (c & 31) * 8;
        *(bf16x8*)&Ps[brow * NP + bd] = *(const bf16x8*)&bp[brow * 256 + bd];
      }
    }

    // Q fragment straight to registers; normalize via cross-fq shfl
    bf16x8 aQ = *(const bf16x8*)&qkv[base + (size_t)(cb * 64 + r0 + fr) * 1536 + hh * 32 + fq * 8];
    {
      float ss = 0.f;
#pragma unroll
      for (int j = 0; j < 8; ++j) { float f = (float)aQ[j]; ss += f * f; }
      ss += __shfl_xor(ss, 16); ss += __shfl_xor(ss, 32);   // sum over fq groups
      float fac = sc / fmaxf(sqrtf(ss), 1e-12f);
#pragma unroll
      for (int j = 0; j < 8; ++j) aQ[j] = (bf16)((float)aQ[j] * fac);
    }
    __syncthreads();   // bias staged

    // S = Q(16x32) @ K^T  (16 rows x 256 cols per wave)
    const f32x4 zero = {0.f, 0.f, 0.f, 0.f};
    f32x4 s[16];
#pragma unroll
    for (int nt = 0; nt < 16; ++nt) {
      bf16x8 bK = *(const bf16x8*)&Ks[(nt * 16 + fr) * KP + fq * 8];
      s[nt] = MFMA(aQ, bK, zero);
    }

    // bias (LDS) + shifted-window mask + softmax
    float rs[4];
#pragma unroll
    for (int r = 0; r < 4; ++r) {
      int lrow = r0 + fq * 4 + r;              // row within 64-row chunk
      int ni = cb * 64 + lrow;                 // query token in window
      int ri = ni >> 4, ci = ni & 15;
      int rgi = (wh == 3) ? (ri < 8 ? 1 : 2) : 0;
      int cgi = (ww == 3) ? (ci < 8 ? 1 : 2) : 0;
      float mx = -1e30f;
#pragma unroll
      for (int nt = 0; nt < 16; ++nt) {
        int nj = nt * 16 + fr;
        int rj = nj >> 4, cj = nj & 15;
        int rgj = (wh == 3) ? (rj < 8 ? 1 : 2) : 0;
        int cgj = (ww == 3) ? (cj < 8 ? 1 : 2) : 0;
        float v = s[nt][r] + (float)Ps[lrow * NP + nj];
        if (rgi != rgj || cgi != cgj) v -= 100.f;
        s[nt][r] = v;
        mx = fmaxf(mx, v);
      }
      mx = fmaxf(mx, __shfl_xor(mx, 1)); mx = fmaxf(mx, __shfl_xor(mx, 2));
      mx = fmaxf(mx, __shfl_xor(mx, 4)); mx = fmaxf(mx, __shfl_xor(mx, 8));
      float sum = 0.f;
#pragma unroll
      for (int nt = 0; nt < 16; ++nt) {
        float p = __expf(s[nt][r] - mx);
        s[nt][r] = p;
        sum += p;
      }
      sum += __shfl_xor(sum, 1); sum += __shfl_xor(sum, 2);
      sum += __shfl_xor(sum, 4); sum += __shfl_xor(sum, 8);
      rs[r] = sum;
    }

    // P -> LDS (each element's writer == its bias reader; no extra barrier)
#pragma unroll
    for (int nt = 0; nt < 16; ++nt)
#pragma unroll
      for (int r = 0; r < 4; ++r)
        Ps[(r0 + fq * 4 + r) * NP + nt * 16 + fr] = (bf16)s[nt][r];
    __syncthreads();   // P visible

    // O = P(16x256) @ V(256x32)
    f32x4 o[2] = {};
#pragma unroll
    for (int ks = 0; ks < 8; ++ks) {
      bf16x8 aP = *(const bf16x8*)&Ps[(r0 + fr) * NP + ks * 32 + fq * 8];
#pragma unroll
      for (int n2 = 0; n2 < 2; ++n2) {
        bf16x8 bV = *(const bf16x8*)&Vt[(n2 * 16 + fr) * NP + ks * 32 + fq * 8];
        o[n2] = MFMA(aP, bV, o[n2]);
      }
    }
#pragma unroll
    for (int n2 = 0; n2 < 2; ++n2)
#pragma unroll
      for (int r = 0; r < 4; ++r) {
        int ni = cb * 64 + r0 + fq * 4 + r;
        attn_out[((size_t)(w * 256 + ni)) * 512 + hh * 32 + n2 * 16 + fr] =
            (bf16)(o[n2][r] / rs[r]);
      }
  }
}

// ---------------- LayerNorm + residual: out = res + LN(vin)
// MODE 0: vin bf16, res float, out bf16   (x1 = x + LN(proj))
// MODE 1: vin bf16, res bf16, out float   (final: x1 + LN(m) -> d_out fp32)
template<int MODE>
__global__ __launch_bounds__(256)
void ln_res_k(const bf16* __restrict__ vin, const void* __restrict__ res,
              const float* __restrict__ gam, const float* __restrict__ bet,
              bf16* __restrict__ outb, float* __restrict__ outf)
{
  const int row = blockIdx.x * 4 + (threadIdx.x >> 6);
  const int lane = threadIdx.x & 63;
  const size_t base = (size_t)row * 512 + lane * 8;
  bf16x8 inv = *(const bf16x8*)(vin + base);
  float v[8];
#pragma unroll
  for (int j = 0; j < 8; ++j) v[j] = (float)inv[j];
  float s = 0.f, s2 = 0.f;
#pragma unroll
  for (int j = 0; j < 8; ++j) { s += v[j]; s2 += v[j] * v[j]; }
#pragma unroll
  for (int d = 1; d < 64; d <<= 1) { s += __shfl_xor(s, d); s2 += __shfl_xor(s2, d); }
  float mean = s * (1.f / 512.f);
  float var = s2 * (1.f / 512.f) - mean * mean;
  float rstd = rsqrtf(var + 1e-5f);

  float rv[8];
  if (MODE == 0) {
    f32x4 ra = *(const f32x4*)((const float*)res + base);
    f32x4 rb = *(const f32x4*)((const float*)res + base + 4);
#pragma unroll
    for (int j = 0; j < 4; ++j) { rv[j] = ra[j]; rv[4 + j] = rb[j]; }
  } else {
    bf16x8 r8 = *(const bf16x8*)((const bf16*)res + base);
#pragma unroll
    for (int j = 0; j < 8; ++j) rv[j] = (float)r8[j];
  }
  f32x4 g1 = *(const f32x4*)(gam + lane * 8);
  f32x4 g2 = *(const f32x4*)(gam + lane * 8 + 4);
  f32x4 b1 = *(const f32x4*)(bet + lane * 8);
  f32x4 b2 = *(const f32x4*)(bet + lane * 8 + 4);

  bf16x8 ob;
  f32x4 o1, o2;
#pragma unroll
  for (int j = 0; j < 8; ++j) {
    float g = (j < 4) ? g1[j] : g2[j - 4];
    float b = (j < 4) ? b1[j] : b2[j - 4];
    float ln = (v[j] - mean) * rstd * g + b;
    float ov = rv[j] + ln;
    if (MODE == 0) ob[j] = (bf16)ov;
    else { if (j < 4) o1[j] = ov; else o2[j - 4] = ov; }
  }
  if (MODE == 0) *(bf16x8*)(outb + base) = ob;
  else { *(f32x4*)(outf + base) = o1; *(f32x4*)(outf + base + 4) = o2; }
}

// ---------------- launch
extern "C" void kernel_launch(void* const* d_in, const int* in_sizes, int n_in,
                              void* d_out, int out_size, void* d_ws, size_t ws_size,
                              hipStream_t stream) {
  const float* x    = (const float*)d_in[0];
  const float* n1g  = (const float*)d_in[3];
  const float* n1b  = (const float*)d_in[4];
  const float* qkvw = (const float*)d_in[5];
  const float* qb   = (const float*)d_in[6];
  const float* vb   = (const float*)d_in[7];
  const float* lsc  = (const float*)d_in[8];
  const float* cw1  = (const float*)d_in[9];
  const float* cb1  = (const float*)d_in[10];
  const float* cw2  = (const float*)d_in[11];
  const float* pw   = (const float*)d_in[12];
  const float* pb   = (const float*)d_in[13];
  const float* n2g  = (const float*)d_in[14];
  const float* n2b  = (const float*)d_in[15];
  const float* f1w  = (const float*)d_in[16];
  const float* f1b  = (const float*)d_in[17];
  const float* f2w  = (const float*)d_in[18];
  const float* f2b  = (const float*)d_in[19];

  // workspace layout (bytes), peak 75.6 MB:
  //   qkvw_b @0            (1,572,864)
  //   pw_b   @1,572,864    (524,288)
  //   f1w_b  @2,097,152    (2,097,152)
  //   f2w_b  @4,194,304    (2,097,152)
  //   btab   @6,291,456    (65,536)
  //   bias16 @6,356,992    (2,097,152)
  //   slotA  @8,454,144    (16,777,216)  xb -> attn_o -> m_buf
  //   slotB  @25,231,360   qkv_t(50.3M); later projo(16.8M) + x1b @42,008,576
  // d_out (33.5 MB float) doubles as FC1 half hidden buffer (bf16).
  char* ws = (char*)d_ws;
  bf16*  qkvw_b = (bf16*)(ws);
  bf16*  pw_b   = (bf16*)(ws + 1572864);
  bf16*  f1w_b  = (bf16*)(ws + 2097152);
  bf16*  f2w_b  = (bf16*)(ws + 4194304);
  float* btab   = (float*)(ws + 6291456);
  bf16*  bias16 = (bf16*)(ws + 6356992);
  bf16*  xb     = (bf16*)(ws + 8454144);
  bf16*  attn_o = (bf16*)(ws + 8454144);
  bf16*  m_buf  = (bf16*)(ws + 8454144);
  bf16*  qkv_t  = (bf16*)(ws + 25231360);
  bf16*  projo  = (bf16*)(ws + 25231360);
  bf16*  x1b    = (bf16*)(ws + 42008576);
  bf16*  h_buf  = (bf16*)d_out;

  // convert inputs to bf16
  f2b_k<<<4096, 256, 0, stream>>>(x, xb, 1048576);
  f2b_k<<<384,  256, 0, stream>>>(qkvw, qkvw_b, 98304);
  f2b_k<<<128,  256, 0, stream>>>(pw, pw_b, 32768);
  f2b_k<<<512,  256, 0, stream>>>(f1w, f1w_b, 131072);
  f2b_k<<<512,  256, 0, stream>>>(f2w, f2w_b, 131072);
  cpb_tbl_k<<<961, 64, 0, stream>>>(cw1, cb1, cw2, btab);
  bias_exp_k<<<512, 256, 0, stream>>>(btab, bias16);

  gemm_k<0><<<dim3(128, 12), 256, 0, stream>>>(xb, qkvw_b, qb, vb, qkv_t, 16384, 1536, 512, 512);
  attn_k<<<dim3(16, 64), 256, 0, stream>>>(qkv_t, bias16, lsc, attn_o);
  gemm_k<1><<<dim3(128, 4), 256, 0, stream>>>(attn_o, pw_b, pb, nullptr, projo, 16384, 512, 512, 512);
  ln_res_k<0><<<4096, 256, 0, stream>>>(projo, x, n1g, n1b, x1b, nullptr);
  // FC1/FC2 split over hidden halves (h in d_out region, 33.5 MB)
  gemm_k<2><<<dim3(128, 8), 256, 0, stream>>>(x1b, f1w_b, f1b, nullptr, h_buf, 16384, 1024, 512, 512);
  gemm_k<3><<<dim3(128, 4), 256, 0, stream>>>(h_buf, f2w_b, f2b, nullptr, m_buf, 16384, 512, 1024, 2048);
  gemm_k<2><<<dim3(128, 8), 256, 0, stream>>>(x1b, f1w_b + 1024 * 512, f1b + 1024, nullptr, h_buf, 16384, 1024, 512, 512);
  gemm_k<4><<<dim3(128, 4), 256, 0, stream>>>(h_buf, f2w_b + 1024, nullptr, nullptr, m_buf, 16384, 512, 1024, 2048);
  ln_res_k<1><<<4096, 256, 0, stream>>>(m_buf, x1b, n2g, n2b, nullptr, (float*)d_out);
}

// Round 6
// 314.436 us; speedup vs baseline: 1.2965x; 1.0144x over previous
//
#include <hip/hip_runtime.h>

typedef __bf16 bf16;
typedef __bf16 bf16x8 __attribute__((ext_vector_type(8)));
typedef float  f32x4  __attribute__((ext_vector_type(4)));

#define MFMA(a, b, c) __builtin_amdgcn_mfma_f32_16x16x32_bf16((a), (b), (c), 0, 0, 0)
#define LOG2E 1.4426950408889634f

__device__ __forceinline__ void gload16(const bf16* g, bf16* l) {
  __builtin_amdgcn_global_load_lds(
      (const __attribute__((address_space(1))) unsigned int*)g,
      (__attribute__((address_space(3))) unsigned int*)l, 16, 0, 0);
}

// ---------------- f32 -> bf16 bulk convert (8 elems/thread)
__global__ __launch_bounds__(256)
void f2b_k(const float* __restrict__ in, bf16* __restrict__ out, int n8)
{
  int i = blockIdx.x * 256 + threadIdx.x;
  if (i >= n8) return;
  f32x4 a = *(const f32x4*)(in + (size_t)i * 8);
  f32x4 b = *(const f32x4*)(in + (size_t)i * 8 + 4);
  bf16x8 o;
#pragma unroll
  for (int j = 0; j < 4; ++j) { o[j] = (bf16)a[j]; o[4 + j] = (bf16)b[j]; }
  *(bf16x8*)(out + (size_t)i * 8) = o;
}

// shifted-window token t = w*256+n  ->  natural token index (b*4096 + gh*64 + gw)
__device__ __forceinline__ int row_map(int t) {
  int w = t >> 8, n = t & 255;
  int b = w >> 4, wi = w & 15;
  int gh = (((wi >> 2) << 4) + (n >> 4) + 8) & 63;
  int gw = (((wi & 3) << 4) + (n & 15) + 8) & 63;
  return (b << 12) + (gh << 6) + gw;
}

// ---------------- GEMM: C[M][N] = A[M][K] @ W[N][K]^T
// double-buffered global_load_lds staging; 128x128 tile, 4 waves
template<int MODE>
__global__ __launch_bounds__(256)
void gemm_k(const bf16* __restrict__ A, const bf16* __restrict__ W,
            const float* __restrict__ b0, const float* __restrict__ b1,
            bf16* __restrict__ outb, int M, int N, int K, int ldw)
{
  __shared__ __align__(16) bf16 As[2][128 * 32];
  __shared__ __align__(16) bf16 Bs[2][128 * 32];
  const int tid  = threadIdx.x;
  const int lane = tid & 63;
  const int wave = tid >> 6;
  const int wr = (wave >> 1) * 64, wc = (wave & 1) * 64;
  const int m0 = blockIdx.x * 128, n0 = blockIdx.y * 128;
  const int fr = lane & 15, fq = lane >> 4;

  f32x4 acc[4][4] = {};

  auto stage = [&](int b, int kt) {
#pragma unroll
    for (int i = 0; i < 2; ++i) {
      int c = tid + i * 256;
      int row = c >> 2, kk = (c & 3) << 3;
      int grow = m0 + row;
      if (MODE == 0) grow = row_map(grow);
      gload16(A + (size_t)grow * K + kt + kk, &As[b][c * 8]);
      gload16(W + (size_t)(n0 + row) * ldw + kt + kk, &Bs[b][c * 8]);
    }
  };

  const int nt = K >> 5;
  stage(0, 0);
  for (int t = 0; t < nt; ++t) {
    __syncthreads();
    if (t + 1 < nt) stage((t + 1) & 1, (t + 1) << 5);
    const int b = t & 1;
    bf16x8 aF[4], bF[4];
#pragma unroll
    for (int m = 0; m < 4; ++m)
      aF[m] = *(const bf16x8*)&As[b][(wr + m * 16 + fr) * 32 + fq * 8];
#pragma unroll
    for (int n = 0; n < 4; ++n)
      bF[n] = *(const bf16x8*)&Bs[b][(wc + n * 16 + fr) * 32 + fq * 8];
#pragma unroll
    for (int m = 0; m < 4; ++m)
#pragma unroll
      for (int n = 0; n < 4; ++n)
        acc[m][n] = MFMA(aF[m], bF[n], acc[m][n]);
  }

#pragma unroll
  for (int m = 0; m < 4; ++m) {
#pragma unroll
    for (int n = 0; n < 4; ++n) {
      int colb = n0 + wc + n * 16 + fr;
      float badd = 0.f;
      if (MODE == 0)
        badd = (colb < 512) ? b0[colb] : (colb < 1024 ? 0.f : b1[colb - 1024]);
      else if (MODE != 4)
        badd = b0[colb];
#pragma unroll
      for (int r = 0; r < 4; ++r) {
        int rowb = m0 + wr + m * 16 + fq * 4 + r;
        float v = acc[m][n][r] + badd;
        size_t oidx;
        if (MODE == 1) oidx = (size_t)row_map(rowb) * N + colb;
        else           oidx = (size_t)rowb * N + colb;
        if (MODE == 2) v = 0.5f * v * (1.f + erff(v * 0.70710678118654752f));
        if (MODE == 4) v += (float)outb[oidx];
        outb[oidx] = (bf16)v;
      }
    }
  }
}

// ---------------- CPB MLP: btab[q][16], q = (dr+15)*31 + (dc+15)
__device__ __forceinline__ float cpb_coord(int r) {
  float t = (float)r * (8.0f / 15.0f);
  float v = log2f(fabsf(t) + 1.0f) * (1.0f / 3.0f);
  return (t < 0.0f) ? -v : v;
}

__global__ __launch_bounds__(64)
void cpb_tbl_k(const float* __restrict__ w1, const float* __restrict__ b1,
               const float* __restrict__ w2, float* __restrict__ btab)
{
  const int q = blockIdx.x;           // 0..960
  const int lane = threadIdx.x;       // 64
  const float t0 = cpb_coord(q / 31 - 15);
  const float t1 = cpb_coord(q % 31 - 15);
  float part[16];
#pragma unroll
  for (int o = 0; o < 16; ++o) part[o] = 0.f;
  for (int jj = 0; jj < 8; ++jj) {
    int j = lane * 8 + jj;
    float hv = t0 * w1[j * 2] + t1 * w1[j * 2 + 1] + b1[j];
    hv = fmaxf(hv, 0.f);
#pragma unroll
    for (int o = 0; o < 16; ++o) part[o] += hv * w2[o * 512 + j];
  }
#pragma unroll
  for (int o = 0; o < 16; ++o) {
#pragma unroll
    for (int d = 1; d < 64; d <<= 1) part[o] += __shfl_xor(part[o], d);
  }
  if (lane == 0) {
#pragma unroll
    for (int o = 0; o < 16; ++o) btab[q * 16 + o] = part[o];
  }
}

// bias_m[h][fr][i][nthi] = (16*sigmoid(rpb[h][i][nthi*16+fr]) - 8) * LOG2E
// swizzled so a softmax lane (fixed fr) reads 16 contiguous bf16 per row i.
__global__ __launch_bounds__(256)
void bias_exp_k(const float* __restrict__ btab, bf16* __restrict__ bias_m)
{
  int e = blockIdx.x * 256 + threadIdx.x;      // < 131072, 8 nthi per thread
  int h = e >> 13, rem = e & 8191;             // rem: fr(4) i(8) half(1)
  int fr = rem >> 9, i = (rem >> 1) & 255, half = rem & 1;
  bf16x8 o;
#pragma unroll
  for (int jj = 0; jj < 8; ++jj) {
    int nthi = half * 8 + jj;
    int q = ((i >> 4) - nthi + 15) * 31 + ((i & 15) - fr + 15);
    float v = (16.f / (1.f + __expf(-btab[q * 16 + h])) - 8.f) * LOG2E;
    o[jj] = (bf16)v;
  }
  *(bf16x8*)&bias_m[(size_t)e * 8] = o;
}

// ---------------- attention: block = (head hh, window w), 256 thr, 4 Q-chunks
// barrier-free main loop: bias in regs (global), P wave-private in LDS.
#define KP 40     // K tile stride
#define NP 260    // V^T / P stride (dw stride 130 = 2 mod 32 -> scalar conflict-free)
__global__ __launch_bounds__(256)
void attn_k(const bf16* __restrict__ qkv, const bf16* __restrict__ bias_m,
            const float* __restrict__ lsc, bf16* __restrict__ attn_out)
{
  const int hh = blockIdx.x;     // 0..15
  const int w  = blockIdx.y;     // 0..63
  const int tid = threadIdx.x, lane = tid & 63, wave = tid >> 6;
  const int fr = lane & 15, fq = lane >> 4;
  const int r0 = wave * 16;

  __shared__ __align__(16) bf16 Ks[256 * KP];
  __shared__ __align__(16) bf16 Vt[32 * NP];
  __shared__ __align__(16) bf16 Ps[64 * NP];   // wave-private P rows

  const size_t base = (size_t)(w * 256) * 1536;
  const float sc = __expf(fminf(lsc[hh], 4.6051701859880914f)) * LOG2E;

  // ---- stage K (cosine-normalized in-flight) and V (transposed), once
#pragma unroll
  for (int i = 0; i < 4; ++i) {
    int c = tid + i * 256;
    int row = c >> 2, d = (c & 3) << 3;     // 4 consecutive lanes share a row
    bf16x8 kv = *(const bf16x8*)&qkv[base + (size_t)row * 1536 + 512 + hh * 32 + d];
    float ss = 0.f;
#pragma unroll
    for (int j = 0; j < 8; ++j) { float f = (float)kv[j]; ss += f * f; }
    ss += __shfl_xor(ss, 1); ss += __shfl_xor(ss, 2);
    float fac = 1.f / fmaxf(sqrtf(ss), 1e-12f);
#pragma unroll
    for (int j = 0; j < 8; ++j) kv[j] = (bf16)((float)kv[j] * fac);
    *(bf16x8*)&Ks[row * KP + d] = kv;
    bf16x8 v = *(const bf16x8*)&qkv[base + (size_t)row * 1536 + 1024 + hh * 32 + d];
#pragma unroll
    for (int j = 0; j < 8; ++j) Vt[(d + j) * NP + row] = v[j];
  }
  __syncthreads();   // K/V visible; ONLY barrier in the kernel

  const bool vrow = ((w >> 2) & 3) == 3, vcol = (w & 3) == 3;

  for (int cb = 0; cb < 4; ++cb) {
    // bias for this lane's 4 rows -> registers (global, L2-hot, swizzled layout)
    bf16x8 br[4][2];
    {
      const bf16* bp = bias_m + (size_t)(((hh * 16 + fr) * 256) + cb * 64 + r0 + fq * 4) * 16;
#pragma unroll
      for (int rr = 0; rr < 4; ++rr) {
        br[rr][0] = *(const bf16x8*)&bp[rr * 16];
        br[rr][1] = *(const bf16x8*)&bp[rr * 16 + 8];
      }
    }

    // Q fragment straight to registers; normalize via cross-fq shfl
    bf16x8 aQ = *(const bf16x8*)&qkv[base + (size_t)(cb * 64 + r0 + fr) * 1536 + hh * 32 + fq * 8];
    {
      float ss = 0.f;
#pragma unroll
      for (int j = 0; j < 8; ++j) { float f = (float)aQ[j]; ss += f * f; }
      ss += __shfl_xor(ss, 16); ss += __shfl_xor(ss, 32);
      float fac = sc / fmaxf(sqrtf(ss), 1e-12f);
#pragma unroll
      for (int j = 0; j < 8; ++j) aQ[j] = (bf16)((float)aQ[j] * fac);
    }

    // S = Q(16x32) @ K^T  (16 rows x 256 cols per wave), log2-domain
    const f32x4 zero = {0.f, 0.f, 0.f, 0.f};
    f32x4 s[16];
#pragma unroll
    for (int nt = 0; nt < 16; ++nt) {
      bf16x8 bK = *(const bf16x8*)&Ks[(nt * 16 + fr) * KP + fq * 8];
      s[nt] = MFMA(aQ, bK, zero);
    }

    // softmax: bias regs + two mask constants per row, exp2
    float rs[4];
#pragma unroll
    for (int r = 0; r < 4; ++r) {
      int ni = cb * 64 + r0 + fq * 4 + r;
      int ri = ni >> 4, ci = ni & 15;
      bool colm = vcol && ((ci < 8) != (fr < 8));
      float m_lo = ((vrow && ri >= 8) || colm) ? -144.2695f : 0.f;  // rgj=1 for nt<8
      float m_hi = ((vrow && ri <  8) || colm) ? -144.2695f : 0.f;  // rgj=2 for nt>=8
      float mx = -1e30f;
#pragma unroll
      for (int nt = 0; nt < 16; ++nt) {
        float b = (float)br[r][nt >> 3][nt & 7];
        float v = s[nt][r] + b + (nt < 8 ? m_lo : m_hi);
        s[nt][r] = v;
        mx = fmaxf(mx, v);
      }
      mx = fmaxf(mx, __shfl_xor(mx, 1)); mx = fmaxf(mx, __shfl_xor(mx, 2));
      mx = fmaxf(mx, __shfl_xor(mx, 4)); mx = fmaxf(mx, __shfl_xor(mx, 8));
      float sum = 0.f;
#pragma unroll
      for (int nt = 0; nt < 16; ++nt) {
        float p = exp2f(s[nt][r] - mx);
        s[nt][r] = p;
        sum += p;
      }
      sum += __shfl_xor(sum, 1); sum += __shfl_xor(sum, 2);
      sum += __shfl_xor(sum, 4); sum += __shfl_xor(sum, 8);
      rs[r] = sum;
    }

    // P -> LDS (wave-private rows; within-wave lgkmcnt ordering suffices)
#pragma unroll
    for (int nt = 0; nt < 16; ++nt)
#pragma unroll
      for (int r = 0; r < 4; ++r)
        Ps[(r0 + fq * 4 + r) * NP + nt * 16 + fr] = (bf16)s[nt][r];

    // O = P(16x256) @ V(256x32)
    f32x4 o[2] = {};
#pragma unroll
    for (int ks = 0; ks < 8; ++ks) {
      bf16x8 aP = *(const bf16x8*)&Ps[(r0 + fr) * NP + ks * 32 + fq * 8];
#pragma unroll
      for (int n2 = 0; n2 < 2; ++n2) {
        bf16x8 bV = *(const bf16x8*)&Vt[(n2 * 16 + fr) * NP + ks * 32 + fq * 8];
        o[n2] = MFMA(aP, bV, o[n2]);
      }
    }
#pragma unroll
    for (int r = 0; r < 4; ++r) {
      float inv = __builtin_amdgcn_rcpf(rs[r]);
      int ni = cb * 64 + r0 + fq * 4 + r;
#pragma unroll
      for (int n2 = 0; n2 < 2; ++n2)
        attn_out[((size_t)(w * 256 + ni)) * 512 + hh * 32 + n2 * 16 + fr] =
            (bf16)(o[n2][r] * inv);
    }
  }
}

// ---------------- LayerNorm + residual: out = res(bf16) + LN(vin)
// MODE 0: out bf16;  MODE 1: out float
template<int MODE>
__global__ __launch_bounds__(256)
void ln_res_k(const bf16* __restrict__ vin, const bf16* __restrict__ res,
              const float* __restrict__ gam, const float* __restrict__ bet,
              bf16* __restrict__ outb, float* __restrict__ outf)
{
  const int row = blockIdx.x * 4 + (threadIdx.x >> 6);
  const int lane = threadIdx.x & 63;
  const size_t base = (size_t)row * 512 + lane * 8;
  bf16x8 inv = *(const bf16x8*)(vin + base);
  float v[8];
#pragma unroll
  for (int j = 0; j < 8; ++j) v[j] = (float)inv[j];
  float s = 0.f, s2 = 0.f;
#pragma unroll
  for (int j = 0; j < 8; ++j) { s += v[j]; s2 += v[j] * v[j]; }
#pragma unroll
  for (int d = 1; d < 64; d <<= 1) { s += __shfl_xor(s, d); s2 += __shfl_xor(s2, d); }
  float mean = s * (1.f / 512.f);
  float var = s2 * (1.f / 512.f) - mean * mean;
  float rstd = rsqrtf(var + 1e-5f);

  bf16x8 r8 = *(const bf16x8*)(res + base);
  f32x4 g1 = *(const f32x4*)(gam + lane * 8);
  f32x4 g2 = *(const f32x4*)(gam + lane * 8 + 4);
  f32x4 b1 = *(const f32x4*)(bet + lane * 8);
  f32x4 b2 = *(const f32x4*)(bet + lane * 8 + 4);

  bf16x8 ob;
  f32x4 o1, o2;
#pragma unroll
  for (int j = 0; j < 8; ++j) {
    float g = (j < 4) ? g1[j] : g2[j - 4];
    float b = (j < 4) ? b1[j] : b2[j - 4];
    float ln = (v[j] - mean) * rstd * g + b;
    float ov = (float)r8[j] + ln;
    if (MODE == 0) ob[j] = (bf16)ov;
    else { if (j < 4) o1[j] = ov; else o2[j - 4] = ov; }
  }
  if (MODE == 0) *(bf16x8*)(outb + base) = ob;
  else { *(f32x4*)(outf + base) = o1; *(f32x4*)(outf + base + 4) = o2; }
}

// ---------------- launch
extern "C" void kernel_launch(void* const* d_in, const int* in_sizes, int n_in,
                              void* d_out, int out_size, void* d_ws, size_t ws_size,
                              hipStream_t stream) {
  const float* x    = (const float*)d_in[0];
  const float* n1g  = (const float*)d_in[3];
  const float* n1b  = (const float*)d_in[4];
  const float* qkvw = (const float*)d_in[5];
  const float* qb   = (const float*)d_in[6];
  const float* vb   = (const float*)d_in[7];
  const float* lsc  = (const float*)d_in[8];
  const float* cw1  = (const float*)d_in[9];
  const float* cb1  = (const float*)d_in[10];
  const float* cw2  = (const float*)d_in[11];
  const float* pw   = (const float*)d_in[12];
  const float* pb   = (const float*)d_in[13];
  const float* n2g  = (const float*)d_in[14];
  const float* n2b  = (const float*)d_in[15];
  const float* f1w  = (const float*)d_in[16];
  const float* f1b  = (const float*)d_in[17];
  const float* f2w  = (const float*)d_in[18];
  const float* f2b  = (const float*)d_in[19];

  // workspace layout (bytes), peak 75.6 MB (proven OK):
  //   qkvw_b @0 (1.57M) | pw_b @1,572,864 (0.52M) | f1w_b @2,097,152 (2.1M)
  //   f2w_b @4,194,304 (2.1M) | btab @6,291,456 (64K) | bias_m @6,356,992 (2.1M)
  //   xb @8,454,144 (16.8M; m_buf reuses after LN1) | qkv_t @25,231,360 (50.3M;
  //   projo reuses) | x1b @42,008,576 (16.8M)
  // d_out: attn_o (16.8M bf16), then h_buf (33.5M bf16), then final f32 out.
  char* ws = (char*)d_ws;
  bf16*  qkvw_b = (bf16*)(ws);
  bf16*  pw_b   = (bf16*)(ws + 1572864);
  bf16*  f1w_b  = (bf16*)(ws + 2097152);
  bf16*  f2w_b  = (bf16*)(ws + 4194304);
  float* btab   = (float*)(ws + 6291456);
  bf16*  bias_m = (bf16*)(ws + 6356992);
  bf16*  xb     = (bf16*)(ws + 8454144);
  bf16*  m_buf  = (bf16*)(ws + 8454144);
  bf16*  qkv_t  = (bf16*)(ws + 25231360);
  bf16*  projo  = (bf16*)(ws + 25231360);
  bf16*  x1b    = (bf16*)(ws + 42008576);
  bf16*  attn_o = (bf16*)d_out;
  bf16*  h_buf  = (bf16*)d_out;

  f2b_k<<<4096, 256, 0, stream>>>(x, xb, 1048576);
  f2b_k<<<384,  256, 0, stream>>>(qkvw, qkvw_b, 98304);
  f2b_k<<<128,  256, 0, stream>>>(pw, pw_b, 32768);
  f2b_k<<<512,  256, 0, stream>>>(f1w, f1w_b, 131072);
  f2b_k<<<512,  256, 0, stream>>>(f2w, f2w_b, 131072);
  cpb_tbl_k<<<961, 64, 0, stream>>>(cw1, cb1, cw2, btab);
  bias_exp_k<<<512, 256, 0, stream>>>(btab, bias_m);

  gemm_k<0><<<dim3(128, 12), 256, 0, stream>>>(xb, qkvw_b, qb, vb, qkv_t, 16384, 1536, 512, 512);
  attn_k<<<dim3(16, 64), 256, 0, stream>>>(qkv_t, bias_m, lsc, attn_o);
  gemm_k<1><<<dim3(128, 4), 256, 0, stream>>>(attn_o, pw_b, pb, nullptr, projo, 16384, 512, 512, 512);
  ln_res_k<0><<<4096, 256, 0, stream>>>(projo, xb, n1g, n1b, x1b, nullptr);
  gemm_k<2><<<dim3(128, 8), 256, 0, stream>>>(x1b, f1w_b, f1b, nullptr, h_buf, 16384, 1024, 512, 512);
  gemm_k<3><<<dim3(128, 4), 256, 0, stream>>>(h_buf, f2w_b, f2b, nullptr, m_buf, 16384, 512, 1024, 2048);
  gemm_k<2><<<dim3(128, 8), 256, 0, stream>>>(x1b, f1w_b + 1024 * 512, f1b + 1024, nullptr, h_buf, 16384, 1024, 512, 512);
  gemm_k<4><<<dim3(128, 4), 256, 0, stream>>>(h_buf, f2w_b + 1024, nullptr, nullptr, m_buf, 16384, 512, 1024, 2048);
  ln_res_k<1><<<4096, 256, 0, stream>>>(m_buf, x1b, n2g, n2b, nullptr, (float*)d_out);
}

// Round 7
// 298.052 us; speedup vs baseline: 1.3678x; 1.0550x over previous
//
#include <hip/hip_runtime.h>

typedef __bf16 bf16;
typedef __bf16 bf16x8 __attribute__((ext_vector_type(8)));
typedef float  f32x4  __attribute__((ext_vector_type(4)));

#define MFMA(a, b, c) __builtin_amdgcn_mfma_f32_16x16x32_bf16((a), (b), (c), 0, 0, 0)
#define LOG2E 1.4426950408889634f

__device__ __forceinline__ void gload16(const bf16* g, bf16* l) {
  __builtin_amdgcn_global_load_lds(
      (const __attribute__((address_space(1))) unsigned int*)g,
      (__attribute__((address_space(3))) unsigned int*)l, 16, 0, 0);
}

// ---------------- f32 -> bf16 bulk convert (8 elems/thread)
__global__ __launch_bounds__(256)
void f2b_k(const float* __restrict__ in, bf16* __restrict__ out, int n8)
{
  int i = blockIdx.x * 256 + threadIdx.x;
  if (i >= n8) return;
  f32x4 a = *(const f32x4*)(in + (size_t)i * 8);
  f32x4 b = *(const f32x4*)(in + (size_t)i * 8 + 4);
  bf16x8 o;
#pragma unroll
  for (int j = 0; j < 4; ++j) { o[j] = (bf16)a[j]; o[4 + j] = (bf16)b[j]; }
  *(bf16x8*)(out + (size_t)i * 8) = o;
}

// shifted-window token t = w*256+n  ->  natural token index (b*4096 + gh*64 + gw)
__device__ __forceinline__ int row_map(int t) {
  int w = t >> 8, n = t & 255;
  int b = w >> 4, wi = w & 15;
  int gh = (((wi >> 2) << 4) + (n >> 4) + 8) & 63;
  int gw = (((wi & 3) << 4) + (n & 15) + 8) & 63;
  return (b << 12) + (gh << 6) + gw;
}

// ---------------- GEMM: C[M][N] = A[M][K] @ W[N][K]^T
// double-buffered global_load_lds staging; 128x128 tile, 4 waves
template<int MODE>
__global__ __launch_bounds__(256)
void gemm_k(const bf16* __restrict__ A, const bf16* __restrict__ W,
            const float* __restrict__ b0, const float* __restrict__ b1,
            bf16* __restrict__ outb, int M, int N, int K, int ldw)
{
  __shared__ __align__(16) bf16 As[2][128 * 32];
  __shared__ __align__(16) bf16 Bs[2][128 * 32];
  const int tid  = threadIdx.x;
  const int lane = tid & 63;
  const int wave = tid >> 6;
  const int wr = (wave >> 1) * 64, wc = (wave & 1) * 64;
  const int m0 = blockIdx.x * 128, n0 = blockIdx.y * 128;
  const int fr = lane & 15, fq = lane >> 4;

  f32x4 acc[4][4] = {};

  auto stage = [&](int b, int kt) {
#pragma unroll
    for (int i = 0; i < 2; ++i) {
      int c = tid + i * 256;
      int row = c >> 2, kk = (c & 3) << 3;
      int grow = m0 + row;
      if (MODE == 0) grow = row_map(grow);
      gload16(A + (size_t)grow * K + kt + kk, &As[b][c * 8]);
      gload16(W + (size_t)(n0 + row) * ldw + kt + kk, &Bs[b][c * 8]);
    }
  };

  const int nt = K >> 5;
  stage(0, 0);
  for (int t = 0; t < nt; ++t) {
    __syncthreads();
    if (t + 1 < nt) stage((t + 1) & 1, (t + 1) << 5);
    const int b = t & 1;
    bf16x8 aF[4], bF[4];
#pragma unroll
    for (int m = 0; m < 4; ++m)
      aF[m] = *(const bf16x8*)&As[b][(wr + m * 16 + fr) * 32 + fq * 8];
#pragma unroll
    for (int n = 0; n < 4; ++n)
      bF[n] = *(const bf16x8*)&Bs[b][(wc + n * 16 + fr) * 32 + fq * 8];
#pragma unroll
    for (int m = 0; m < 4; ++m)
#pragma unroll
      for (int n = 0; n < 4; ++n)
        acc[m][n] = MFMA(aF[m], bF[n], acc[m][n]);
  }

#pragma unroll
  for (int m = 0; m < 4; ++m) {
#pragma unroll
    for (int n = 0; n < 4; ++n) {
      int colb = n0 + wc + n * 16 + fr;
      float badd = 0.f;
      if (MODE == 0)
        badd = (colb < 512) ? b0[colb] : (colb < 1024 ? 0.f : b1[colb - 1024]);
      else if (MODE != 4)
        badd = b0[colb];
#pragma unroll
      for (int r = 0; r < 4; ++r) {
        int rowb = m0 + wr + m * 16 + fq * 4 + r;
        float v = acc[m][n][r] + badd;
        size_t oidx;
        if (MODE == 1) oidx = (size_t)row_map(rowb) * N + colb;
        else           oidx = (size_t)rowb * N + colb;
        if (MODE == 2) v = 0.5f * v * (1.f + erff(v * 0.70710678118654752f));
        if (MODE == 4) v += (float)outb[oidx];
        outb[oidx] = (bf16)v;
      }
    }
  }
}

// ---------------- CPB MLP: btab[q][16], q = (dr+15)*31 + (dc+15)
__device__ __forceinline__ float cpb_coord(int r) {
  float t = (float)r * (8.0f / 15.0f);
  float v = log2f(fabsf(t) + 1.0f) * (1.0f / 3.0f);
  return (t < 0.0f) ? -v : v;
}

__global__ __launch_bounds__(64)
void cpb_tbl_k(const float* __restrict__ w1, const float* __restrict__ b1,
               const float* __restrict__ w2, float* __restrict__ btab)
{
  const int q = blockIdx.x;           // 0..960
  const int lane = threadIdx.x;       // 64
  const float t0 = cpb_coord(q / 31 - 15);
  const float t1 = cpb_coord(q % 31 - 15);
  float part[16];
#pragma unroll
  for (int o = 0; o < 16; ++o) part[o] = 0.f;
  for (int jj = 0; jj < 8; ++jj) {
    int j = lane * 8 + jj;
    float hv = t0 * w1[j * 2] + t1 * w1[j * 2 + 1] + b1[j];
    hv = fmaxf(hv, 0.f);
#pragma unroll
    for (int o = 0; o < 16; ++o) part[o] += hv * w2[o * 512 + j];
  }
#pragma unroll
  for (int o = 0; o < 16; ++o) {
#pragma unroll
    for (int d = 1; d < 64; d <<= 1) part[o] += __shfl_xor(part[o], d);
  }
  if (lane == 0) {
#pragma unroll
    for (int o = 0; o < 16; ++o) btab[q * 16 + o] = part[o];
  }
}

// bias_m[h][fr][i][nthi] = (16*sigmoid(rpb[h][i][nthi*16+fr]) - 8) * LOG2E
// swizzled so a softmax lane (fixed fr) reads 16 contiguous bf16 per row i.
__global__ __launch_bounds__(256)
void bias_exp_k(const float* __restrict__ btab, bf16* __restrict__ bias_m)
{
  int e = blockIdx.x * 256 + threadIdx.x;      // < 131072, 8 nthi per thread
  int h = e >> 13, rem = e & 8191;             // rem: fr(4) i(8) half(1)
  int fr = rem >> 9, i = (rem >> 1) & 255, half = rem & 1;
  bf16x8 o;
#pragma unroll
  for (int jj = 0; jj < 8; ++jj) {
    int nthi = half * 8 + jj;
    int q = ((i >> 4) - nthi + 15) * 31 + ((i & 15) - fr + 15);
    float v = (16.f / (1.f + __expf(-btab[q * 16 + h])) - 8.f) * LOG2E;
    o[jj] = (bf16)v;
  }
  *(bf16x8*)&bias_m[(size_t)e * 8] = o;
}

// ---------------- attention: block = (head hh, window w), 256 thr, 4 Q-chunks
// fixed-shift exp2 softmax (no max pass); k processed in 2 halves of 128 so
// Ps is half-size; LDS = 51,968 B -> 3 blocks/CU.
#define KP 36     // K tile stride
#define VP 260    // V^T stride
#define PP 132    // P tile stride (k-half)
__global__ __launch_bounds__(256)
void attn_k(const bf16* __restrict__ qkv, const bf16* __restrict__ bias_m,
            const float* __restrict__ lsc, bf16* __restrict__ attn_out)
{
  const int hh = blockIdx.x;     // 0..15
  const int w  = blockIdx.y;     // 0..63
  const int tid = threadIdx.x, lane = tid & 63, wave = tid >> 6;
  const int fr = lane & 15, fq = lane >> 4;
  const int r0 = wave * 16;

  __shared__ __align__(16) bf16 Ks[256 * KP];   // 18,432 B
  __shared__ __align__(16) bf16 Vt[32 * VP];    // 16,640 B
  __shared__ __align__(16) bf16 Ps[64 * PP];    // 16,896 B (wave-private rows)

  const size_t base = (size_t)(w * 256) * 1536;
  const float sc2 = __expf(fminf(lsc[hh], 4.6051701859880914f)) * LOG2E;
  const float shift = sc2 + 12.0f;   // fixed softmax shift (log2 domain)

  // ---- stage K (cosine-normalized in-flight) and V (transposed), once
#pragma unroll
  for (int i = 0; i < 4; ++i) {
    int c = tid + i * 256;
    int row = c >> 2, d = (c & 3) << 3;     // 4 consecutive lanes share a row
    bf16x8 kv = *(const bf16x8*)&qkv[base + (size_t)row * 1536 + 512 + hh * 32 + d];
    float ss = 0.f;
#pragma unroll
    for (int j = 0; j < 8; ++j) { float f = (float)kv[j]; ss += f * f; }
    ss += __shfl_xor(ss, 1); ss += __shfl_xor(ss, 2);
    float fac = 1.f / fmaxf(sqrtf(ss), 1e-12f);
#pragma unroll
    for (int j = 0; j < 8; ++j) kv[j] = (bf16)((float)kv[j] * fac);
    *(bf16x8*)&Ks[row * KP + d] = kv;
    bf16x8 v = *(const bf16x8*)&qkv[base + (size_t)row * 1536 + 1024 + hh * 32 + d];
#pragma unroll
    for (int j = 0; j < 8; ++j) Vt[(d + j) * VP + row] = v[j];
  }
  __syncthreads();   // K/V visible; ONLY barrier in the kernel

  const bool vrow = ((w >> 2) & 3) == 3, vcol = (w & 3) == 3;
  const f32x4 zero = {0.f, 0.f, 0.f, 0.f};

  for (int cb = 0; cb < 4; ++cb) {
    // Q fragment straight to registers; normalize via cross-fq shfl
    bf16x8 aQ = *(const bf16x8*)&qkv[base + (size_t)(cb * 64 + r0 + fr) * 1536 + hh * 32 + fq * 8];
    {
      float ss = 0.f;
#pragma unroll
      for (int j = 0; j < 8; ++j) { float f = (float)aQ[j]; ss += f * f; }
      ss += __shfl_xor(ss, 16); ss += __shfl_xor(ss, 32);
      float fac = sc2 / fmaxf(sqrtf(ss), 1e-12f);
#pragma unroll
      for (int j = 0; j < 8; ++j) aQ[j] = (bf16)((float)aQ[j] * fac);
    }

    float rs[4] = {0.f, 0.f, 0.f, 0.f};
    f32x4 o[2] = {};

#pragma unroll
    for (int kh = 0; kh < 2; ++kh) {
      // bias for this lane's 4 rows, this k-half -> registers
      bf16x8 br[4];
      {
        const bf16* bp = bias_m +
            (size_t)(((hh * 16 + fr) * 256) + cb * 64 + r0 + fq * 4) * 16 + kh * 8;
#pragma unroll
        for (int rr = 0; rr < 4; ++rr) br[rr] = *(const bf16x8*)&bp[rr * 16];
      }

      // S half: Q(16x32) @ K^T (16 rows x 128 cols per wave)
      f32x4 s[8];
#pragma unroll
      for (int nt = 0; nt < 8; ++nt) {
        bf16x8 bK = *(const bf16x8*)&Ks[((kh * 8 + nt) * 16 + fr) * KP + fq * 8];
        s[nt] = MFMA(aQ, bK, zero);
      }

      // fixed-shift softmax: p = exp2(s + bias + c), c per (row, half)
#pragma unroll
      for (int r = 0; r < 4; ++r) {
        int ni = cb * 64 + r0 + fq * 4 + r;
        int ri = ni >> 4, ci = ni & 15;
        bool colm = vcol && ((ci < 8) != (fr < 8));
        bool rowm = vrow && ((ri < 8) != (kh == 0));
        float c = ((colm || rowm) ? -144.2695f : 0.f) - shift;
        float part = 0.f;
#pragma unroll
        for (int nt = 0; nt < 8; ++nt) {
          float p = __builtin_amdgcn_exp2f(s[nt][r] + (float)br[r][nt] + c);
          s[nt][r] = p;
          part += p;
        }
        rs[r] += part;
      }

      // P half -> LDS (wave-private rows; within-wave lgkmcnt ordering suffices)
#pragma unroll
      for (int nt = 0; nt < 8; ++nt)
#pragma unroll
        for (int r = 0; r < 4; ++r)
          Ps[(r0 + fq * 4 + r) * PP + nt * 16 + fr] = (bf16)s[nt][r];

      // O += P_half(16x128) @ V_half(128x32)
#pragma unroll
      for (int ks = 0; ks < 4; ++ks) {
        bf16x8 aP = *(const bf16x8*)&Ps[(r0 + fr) * PP + ks * 32 + fq * 8];
#pragma unroll
        for (int n2 = 0; n2 < 2; ++n2) {
          bf16x8 bV = *(const bf16x8*)&Vt[(n2 * 16 + fr) * VP + kh * 128 + ks * 32 + fq * 8];
          o[n2] = MFMA(aP, bV, o[n2]);
        }
      }
    }

    // row-sum reduce (once per chunk) and store
#pragma unroll
    for (int r = 0; r < 4; ++r) {
      float sum = rs[r];
      sum += __shfl_xor(sum, 1); sum += __shfl_xor(sum, 2);
      sum += __shfl_xor(sum, 4); sum += __shfl_xor(sum, 8);
      float inv = __builtin_amdgcn_rcpf(sum);
      int ni = cb * 64 + r0 + fq * 4 + r;
#pragma unroll
      for (int n2 = 0; n2 < 2; ++n2)
        attn_out[((size_t)(w * 256 + ni)) * 512 + hh * 32 + n2 * 16 + fr] =
            (bf16)(o[n2][r] * inv);
    }
  }
}

// ---------------- LayerNorm + residual: out = res(bf16) + LN(vin)
// MODE 0: out bf16;  MODE 1: out float
template<int MODE>
__global__ __launch_bounds__(256)
void ln_res_k(const bf16* __restrict__ vin, const bf16* __restrict__ res,
              const float* __restrict__ gam, const float* __restrict__ bet,
              bf16* __restrict__ outb, float* __restrict__ outf)
{
  const int row = blockIdx.x * 4 + (threadIdx.x >> 6);
  const int lane = threadIdx.x & 63;
  const size_t base = (size_t)row * 512 + lane * 8;
  bf16x8 inv = *(const bf16x8*)(vin + base);
  float v[8];
#pragma unroll
  for (int j = 0; j < 8; ++j) v[j] = (float)inv[j];
  float s = 0.f, s2 = 0.f;
#pragma unroll
  for (int j = 0; j < 8; ++j) { s += v[j]; s2 += v[j] * v[j]; }
#pragma unroll
  for (int d = 1; d < 64; d <<= 1) { s += __shfl_xor(s, d); s2 += __shfl_xor(s2, d); }
  float mean = s * (1.f / 512.f);
  float var = s2 * (1.f / 512.f) - mean * mean;
  float rstd = rsqrtf(var + 1e-5f);

  bf16x8 r8 = *(const bf16x8*)(res + base);
  f32x4 g1 = *(const f32x4*)(gam + lane * 8);
  f32x4 g2 = *(const f32x4*)(gam + lane * 8 + 4);
  f32x4 b1 = *(const f32x4*)(bet + lane * 8);
  f32x4 b2 = *(const f32x4*)(bet + lane * 8 + 4);

  bf16x8 ob;
  f32x4 o1, o2;
#pragma unroll
  for (int j = 0; j < 8; ++j) {
    float g = (j < 4) ? g1[j] : g2[j - 4];
    float b = (j < 4) ? b1[j] : b2[j - 4];
    float ln = (v[j] - mean) * rstd * g + b;
    float ov = (float)r8[j] + ln;
    if (MODE == 0) ob[j] = (bf16)ov;
    else { if (j < 4) o1[j] = ov; else o2[j - 4] = ov; }
  }
  if (MODE == 0) *(bf16x8*)(outb + base) = ob;
  else { *(f32x4*)(outf + base) = o1; *(f32x4*)(outf + base + 4) = o2; }
}

// ---------------- launch
extern "C" void kernel_launch(void* const* d_in, const int* in_sizes, int n_in,
                              void* d_out, int out_size, void* d_ws, size_t ws_size,
                              hipStream_t stream) {
  const float* x    = (const float*)d_in[0];
  const float* n1g  = (const float*)d_in[3];
  const float* n1b  = (const float*)d_in[4];
  const float* qkvw = (const float*)d_in[5];
  const float* qb   = (const float*)d_in[6];
  const float* vb   = (const float*)d_in[7];
  const float* lsc  = (const float*)d_in[8];
  const float* cw1  = (const float*)d_in[9];
  const float* cb1  = (const float*)d_in[10];
  const float* cw2  = (const float*)d_in[11];
  const float* pw   = (const float*)d_in[12];
  const float* pb   = (const float*)d_in[13];
  const float* n2g  = (const float*)d_in[14];
  const float* n2b  = (const float*)d_in[15];
  const float* f1w  = (const float*)d_in[16];
  const float* f1b  = (const float*)d_in[17];
  const float* f2w  = (const float*)d_in[18];
  const float* f2b  = (const float*)d_in[19];

  // workspace layout (bytes), peak 75.6 MB (proven OK):
  //   qkvw_b @0 (1.57M) | pw_b @1,572,864 (0.52M) | f1w_b @2,097,152 (2.1M)
  //   f2w_b @4,194,304 (2.1M) | btab @6,291,456 (64K) | bias_m @6,356,992 (2.1M)
  //   xb @8,454,144 (16.8M; m_buf reuses after LN1) | qkv_t @25,231,360 (50.3M;
  //   projo reuses) | x1b @42,008,576 (16.8M)
  // d_out: attn_o (16.8M bf16), then h_buf (33.5M bf16), then final f32 out.
  char* ws = (char*)d_ws;
  bf16*  qkvw_b = (bf16*)(ws);
  bf16*  pw_b   = (bf16*)(ws + 1572864);
  bf16*  f1w_b  = (bf16*)(ws + 2097152);
  bf16*  f2w_b  = (bf16*)(ws + 4194304);
  float* btab   = (float*)(ws + 6291456);
  bf16*  bias_m = (bf16*)(ws + 6356992);
  bf16*  xb     = (bf16*)(ws + 8454144);
  bf16*  m_buf  = (bf16*)(ws + 8454144);
  bf16*  qkv_t  = (bf16*)(ws + 25231360);
  bf16*  projo  = (bf16*)(ws + 25231360);
  bf16*  x1b    = (bf16*)(ws + 42008576);
  bf16*  attn_o = (bf16*)d_out;
  bf16*  h_buf  = (bf16*)d_out;

  f2b_k<<<4096, 256, 0, stream>>>(x, xb, 1048576);
  f2b_k<<<384,  256, 0, stream>>>(qkvw, qkvw_b, 98304);
  f2b_k<<<128,  256, 0, stream>>>(pw, pw_b, 32768);
  f2b_k<<<512,  256, 0, stream>>>(f1w, f1w_b, 131072);
  f2b_k<<<512,  256, 0, stream>>>(f2w, f2w_b, 131072);
  cpb_tbl_k<<<961, 64, 0, stream>>>(cw1, cb1, cw2, btab);
  bias_exp_k<<<512, 256, 0, stream>>>(btab, bias_m);

  gemm_k<0><<<dim3(128, 12), 256, 0, stream>>>(xb, qkvw_b, qb, vb, qkv_t, 16384, 1536, 512, 512);
  attn_k<<<dim3(16, 64), 256, 0, stream>>>(qkv_t, bias_m, lsc, attn_o);
  gemm_k<1><<<dim3(128, 4), 256, 0, stream>>>(attn_o, pw_b, pb, nullptr, projo, 16384, 512, 512, 512);
  ln_res_k<0><<<4096, 256, 0, stream>>>(projo, xb, n1g, n1b, x1b, nullptr);
  gemm_k<2><<<dim3(128, 8), 256, 0, stream>>>(x1b, f1w_b, f1b, nullptr, h_buf, 16384, 1024, 512, 512);
  gemm_k<3><<<dim3(128, 4), 256, 0, stream>>>(h_buf, f2w_b, f2b, nullptr, m_buf, 16384, 512, 1024, 2048);
  gemm_k<2><<<dim3(128, 8), 256, 0, stream>>>(x1b, f1w_b + 1024 * 512, f1b + 1024, nullptr, h_buf, 16384, 1024, 512, 512);
  gemm_k<4><<<dim3(128, 4), 256, 0, stream>>>(h_buf, f2w_b + 1024, nullptr, nullptr, m_buf, 16384, 512, 1024, 2048);
  ln_res_k<1><<<4096, 256, 0, stream>>>(m_buf, x1b, n2g, n2b, nullptr, (float*)d_out);
}

// Round 8
// 245.827 us; speedup vs baseline: 1.6584x; 1.2124x over previous
//
#include <hip/hip_runtime.h>

typedef __bf16 bf16;
typedef __bf16 bf16x8 __attribute__((ext_vector_type(8)));
typedef float  f32x4  __attribute__((ext_vector_type(4)));

#define MFMA(a, b, c) __builtin_amdgcn_mfma_f32_16x16x32_bf16((a), (b), (c), 0, 0, 0)
#define LOG2E 1.4426950408889634f

__device__ __forceinline__ void gload16(const bf16* g, bf16* l) {
  __builtin_amdgcn_global_load_lds(
      (const __attribute__((address_space(1))) unsigned int*)g,
      (__attribute__((address_space(3))) unsigned int*)l, 16, 0, 0);
}

// ---------------- f32 -> bf16 bulk convert (8 elems/thread)
__global__ __launch_bounds__(256)
void f2b_k(const float* __restrict__ in, bf16* __restrict__ out, int n8)
{
  int i = blockIdx.x * 256 + threadIdx.x;
  if (i >= n8) return;
  f32x4 a = *(const f32x4*)(in + (size_t)i * 8);
  f32x4 b = *(const f32x4*)(in + (size_t)i * 8 + 4);
  bf16x8 o;
#pragma unroll
  for (int j = 0; j < 4; ++j) { o[j] = (bf16)a[j]; o[4 + j] = (bf16)b[j]; }
  *(bf16x8*)(out + (size_t)i * 8) = o;
}

// shifted-window token t = w*256+n  ->  natural token index (b*4096 + gh*64 + gw)
__device__ __forceinline__ int row_map(int t) {
  int w = t >> 8, n = t & 255;
  int b = w >> 4, wi = w & 15;
  int gh = (((wi >> 2) << 4) + (n >> 4) + 8) & 63;
  int gw = (((wi & 3) << 4) + (n & 15) + 8) & 63;
  return (b << 12) + (gh << 6) + gw;
}

// ---------------- GEMM v2: 128x128 tile, BK=64, 512 thr (8 waves 2Mx4N),
// raw-barrier + explicit vmcnt(0) once per K-tile; XOR-swizzled LDS
// (pre-swizzled global source slot, linear gload_lds dest, swizzled ds_read).
// MODE 0: QKV  (A row-gather via row_map, bias=concat(qb,0,vb))
// MODE 1: PROJ (bias, out rows scattered via row_map)
// MODE 2: FC1  (bias + exact GELU, out split h0/h1 by column half, ldc=1024)
// MODE 3: FC2  (bias, A split h0/h1 by k half, K=2048)
template<int MODE>
__global__ __launch_bounds__(512)
void gemm2_k(const bf16* __restrict__ A0, const bf16* __restrict__ A1,
             const bf16* __restrict__ W,
             const float* __restrict__ b0, const float* __restrict__ b1,
             bf16* __restrict__ out0, bf16* __restrict__ out1,
             int K, int lda, int ldw, int ldc)
{
  __shared__ __align__(16) bf16 As[2][128 * 64];   // 32 KB
  __shared__ __align__(16) bf16 Bs[2][128 * 64];   // 32 KB
  const int tid  = threadIdx.x;
  const int lane = tid & 63;
  const int wave = tid >> 6;
  const int wm = wave >> 2, wn = wave & 3;         // 2 x 4 waves
  const int fr = lane & 15, fq = lane >> 4;
  const int m0 = blockIdx.x * 128, n0 = blockIdx.y * 128;

  f32x4 acc[4][2] = {};

  auto stage = [&](int buf, int t) {
    const int kb = t << 6;
#pragma unroll
    for (int i = 0; i < 2; ++i) {
      int c = tid + i * 512;                 // chunk 0..1023 (16B each)
      int row = c >> 3, sl = c & 7;
      int kk = ((sl ^ (row & 7)) << 3);      // swizzled source slot
      int arow = m0 + row;
      if (MODE == 0) arow = row_map(arow);
      const bf16* ap;
      if (MODE == 3) {
        const bf16* Ab = (kb < 1024) ? A0 : A1;
        ap = Ab + (size_t)arow * lda + (kb & 1023) + kk;
      } else {
        ap = A0 + (size_t)arow * lda + kb + kk;
      }
      gload16(ap, &As[buf][c * 8]);
      gload16(W + (size_t)(n0 + row) * ldw + kb + kk, &Bs[buf][c * 8]);
    }
  };

  const int nt = K >> 6;
  stage(0, 0);
  for (int t = 0; t < nt; ++t) {
    asm volatile("s_waitcnt vmcnt(0)" ::: "memory");   // own stage loads landed
    asm volatile("s_barrier" ::: "memory");            // all waves staged; prev readers done
    if (t + 1 < nt) stage((t + 1) & 1, t + 1);         // loads fly over whole tile's MFMA
    const bf16* as = As[t & 1];
    const bf16* bs = Bs[t & 1];
#pragma unroll
    for (int k2 = 0; k2 < 2; ++k2) {
      const int sw = ((k2 * 4 + fq) ^ (fr & 7)) << 3;
      bf16x8 bF[2];
#pragma unroll
      for (int n = 0; n < 2; ++n)
        bF[n] = *(const bf16x8*)&bs[(wn * 32 + n * 16 + fr) * 64 + sw];
#pragma unroll
      for (int m = 0; m < 4; ++m) {
        bf16x8 aF = *(const bf16x8*)&as[(wm * 64 + m * 16 + fr) * 64 + sw];
#pragma unroll
        for (int n = 0; n < 2; ++n)
          acc[m][n] = MFMA(aF, bF[n], acc[m][n]);
      }
    }
  }

#pragma unroll
  for (int m = 0; m < 4; ++m) {
#pragma unroll
    for (int n = 0; n < 2; ++n) {
      int colb = n0 + wn * 32 + n * 16 + fr;
      float badd;
      if (MODE == 0)
        badd = (colb < 512) ? b0[colb] : (colb < 1024 ? 0.f : b1[colb - 1024]);
      else
        badd = b0[colb];
#pragma unroll
      for (int r = 0; r < 4; ++r) {
        int rowb = m0 + wm * 64 + m * 16 + fq * 4 + r;
        float v = acc[m][n][r] + badd;
        if (MODE == 0) out0[(size_t)rowb * ldc + colb] = (bf16)v;
        if (MODE == 1) out0[(size_t)row_map(rowb) * ldc + colb] = (bf16)v;
        if (MODE == 2) {
          v = 0.5f * v * (1.f + erff(v * 0.70710678118654752f));
          bf16* ob = (colb < 1024) ? out0 : out1;
          ob[(size_t)rowb * 1024 + (colb & 1023)] = (bf16)v;
        }
        if (MODE == 3) out0[(size_t)rowb * ldc + colb] = (bf16)v;
      }
    }
  }
}

// ---------------- CPB MLP: btab[q][16], q = (dr+15)*31 + (dc+15)
__device__ __forceinline__ float cpb_coord(int r) {
  float t = (float)r * (8.0f / 15.0f);
  float v = log2f(fabsf(t) + 1.0f) * (1.0f / 3.0f);
  return (t < 0.0f) ? -v : v;
}

__global__ __launch_bounds__(64)
void cpb_tbl_k(const float* __restrict__ w1, const float* __restrict__ b1,
               const float* __restrict__ w2, float* __restrict__ btab)
{
  const int q = blockIdx.x;           // 0..960
  const int lane = threadIdx.x;       // 64
  const float t0 = cpb_coord(q / 31 - 15);
  const float t1 = cpb_coord(q % 31 - 15);
  float part[16];
#pragma unroll
  for (int o = 0; o < 16; ++o) part[o] = 0.f;
  for (int jj = 0; jj < 8; ++jj) {
    int j = lane * 8 + jj;
    float hv = t0 * w1[j * 2] + t1 * w1[j * 2 + 1] + b1[j];
    hv = fmaxf(hv, 0.f);
#pragma unroll
    for (int o = 0; o < 16; ++o) part[o] += hv * w2[o * 512 + j];
  }
#pragma unroll
  for (int o = 0; o < 16; ++o) {
#pragma unroll
    for (int d = 1; d < 64; d <<= 1) part[o] += __shfl_xor(part[o], d);
  }
  if (lane == 0) {
#pragma unroll
    for (int o = 0; o < 16; ++o) btab[q * 16 + o] = part[o];
  }
}

// bias_m[h][fr][i][nthi] = (16*sigmoid(rpb[h][i][nthi*16+fr]) - 8) * LOG2E
__global__ __launch_bounds__(256)
void bias_exp_k(const float* __restrict__ btab, bf16* __restrict__ bias_m)
{
  int e = blockIdx.x * 256 + threadIdx.x;      // < 131072, 8 nthi per thread
  int h = e >> 13, rem = e & 8191;             // rem: fr(4) i(8) half(1)
  int fr = rem >> 9, i = (rem >> 1) & 255, half = rem & 1;
  bf16x8 o;
#pragma unroll
  for (int jj = 0; jj < 8; ++jj) {
    int nthi = half * 8 + jj;
    int q = ((i >> 4) - nthi + 15) * 31 + ((i & 15) - fr + 15);
    float v = (16.f / (1.f + __expf(-btab[q * 16 + h])) - 8.f) * LOG2E;
    o[jj] = (bf16)v;
  }
  *(bf16x8*)&bias_m[(size_t)e * 8] = o;
}

// ---------------- attention: block = (head hh, window w), 256 thr, 4 Q-chunks
// fixed-shift exp2 softmax; k in 2 halves of 128; LDS 51,968 B -> 3 blocks/CU.
#define KP 36
#define VP 260
#define PP 132
__global__ __launch_bounds__(256)
void attn_k(const bf16* __restrict__ qkv, const bf16* __restrict__ bias_m,
            const float* __restrict__ lsc, bf16* __restrict__ attn_out)
{
  const int hh = blockIdx.x;     // 0..15
  const int w  = blockIdx.y;     // 0..63
  const int tid = threadIdx.x, lane = tid & 63, wave = tid >> 6;
  const int fr = lane & 15, fq = lane >> 4;
  const int r0 = wave * 16;

  __shared__ __align__(16) bf16 Ks[256 * KP];
  __shared__ __align__(16) bf16 Vt[32 * VP];
  __shared__ __align__(16) bf16 Ps[64 * PP];

  const size_t base = (size_t)(w * 256) * 1536;
  const float sc2 = __expf(fminf(lsc[hh], 4.6051701859880914f)) * LOG2E;
  const float shift = sc2 + 12.0f;

#pragma unroll
  for (int i = 0; i < 4; ++i) {
    int c = tid + i * 256;
    int row = c >> 2, d = (c & 3) << 3;
    bf16x8 kv = *(const bf16x8*)&qkv[base + (size_t)row * 1536 + 512 + hh * 32 + d];
    float ss = 0.f;
#pragma unroll
    for (int j = 0; j < 8; ++j) { float f = (float)kv[j]; ss += f * f; }
    ss += __shfl_xor(ss, 1); ss += __shfl_xor(ss, 2);
    float fac = 1.f / fmaxf(sqrtf(ss), 1e-12f);
#pragma unroll
    for (int j = 0; j < 8; ++j) kv[j] = (bf16)((float)kv[j] * fac);
    *(bf16x8*)&Ks[row * KP + d] = kv;
    bf16x8 v = *(const bf16x8*)&qkv[base + (size_t)row * 1536 + 1024 + hh * 32 + d];
#pragma unroll
    for (int j = 0; j < 8; ++j) Vt[(d + j) * VP + row] = v[j];
  }
  __syncthreads();

  const bool vrow = ((w >> 2) & 3) == 3, vcol = (w & 3) == 3;
  const f32x4 zero = {0.f, 0.f, 0.f, 0.f};

  for (int cb = 0; cb < 4; ++cb) {
    bf16x8 aQ = *(const bf16x8*)&qkv[base + (size_t)(cb * 64 + r0 + fr) * 1536 + hh * 32 + fq * 8];
    {
      float ss = 0.f;
#pragma unroll
      for (int j = 0; j < 8; ++j) { float f = (float)aQ[j]; ss += f * f; }
      ss += __shfl_xor(ss, 16); ss += __shfl_xor(ss, 32);
      float fac = sc2 / fmaxf(sqrtf(ss), 1e-12f);
#pragma unroll
      for (int j = 0; j < 8; ++j) aQ[j] = (bf16)((float)aQ[j] * fac);
    }

    float rs[4] = {0.f, 0.f, 0.f, 0.f};
    f32x4 o[2] = {};

#pragma unroll
    for (int kh = 0; kh < 2; ++kh) {
      bf16x8 br[4];
      {
        const bf16* bp = bias_m +
            (size_t)(((hh * 16 + fr) * 256) + cb * 64 + r0 + fq * 4) * 16 + kh * 8;
#pragma unroll
        for (int rr = 0; rr < 4; ++rr) br[rr] = *(const bf16x8*)&bp[rr * 16];
      }

      f32x4 s[8];
#pragma unroll
      for (int nt = 0; nt < 8; ++nt) {
        bf16x8 bK = *(const bf16x8*)&Ks[((kh * 8 + nt) * 16 + fr) * KP + fq * 8];
        s[nt] = MFMA(aQ, bK, zero);
      }

#pragma unroll
      for (int r = 0; r < 4; ++r) {
        int ni = cb * 64 + r0 + fq * 4 + r;
        int ri = ni >> 4, ci = ni & 15;
        bool colm = vcol && ((ci < 8) != (fr < 8));
        bool rowm = vrow && ((ri < 8) != (kh == 0));
        float c = ((colm || rowm) ? -144.2695f : 0.f) - shift;
        float part = 0.f;
#pragma unroll
        for (int nt = 0; nt < 8; ++nt) {
          float p = __builtin_amdgcn_exp2f(s[nt][r] + (float)br[r][nt] + c);
          s[nt][r] = p;
          part += p;
        }
        rs[r] += part;
      }

#pragma unroll
      for (int nt = 0; nt < 8; ++nt)
#pragma unroll
        for (int r = 0; r < 4; ++r)
          Ps[(r0 + fq * 4 + r) * PP + nt * 16 + fr] = (bf16)s[nt][r];

#pragma unroll
      for (int ks = 0; ks < 4; ++ks) {
        bf16x8 aP = *(const bf16x8*)&Ps[(r0 + fr) * PP + ks * 32 + fq * 8];
#pragma unroll
        for (int n2 = 0; n2 < 2; ++n2) {
          bf16x8 bV = *(const bf16x8*)&Vt[(n2 * 16 + fr) * VP + kh * 128 + ks * 32 + fq * 8];
          o[n2] = MFMA(aP, bV, o[n2]);
        }
      }
    }

#pragma unroll
    for (int r = 0; r < 4; ++r) {
      float sum = rs[r];
      sum += __shfl_xor(sum, 1); sum += __shfl_xor(sum, 2);
      sum += __shfl_xor(sum, 4); sum += __shfl_xor(sum, 8);
      float inv = __builtin_amdgcn_rcpf(sum);
      int ni = cb * 64 + r0 + fq * 4 + r;
#pragma unroll
      for (int n2 = 0; n2 < 2; ++n2)
        attn_out[((size_t)(w * 256 + ni)) * 512 + hh * 32 + n2 * 16 + fr] =
            (bf16)(o[n2][r] * inv);
    }
  }
}

// ---------------- LayerNorm + residual: out = res(bf16) + LN(vin)
template<int MODE>
__global__ __launch_bounds__(256)
void ln_res_k(const bf16* __restrict__ vin, const bf16* __restrict__ res,
              const float* __restrict__ gam, const float* __restrict__ bet,
              bf16* __restrict__ outb, float* __restrict__ outf)
{
  const int row = blockIdx.x * 4 + (threadIdx.x >> 6);
  const int lane = threadIdx.x & 63;
  const size_t base = (size_t)row * 512 + lane * 8;
  bf16x8 inv = *(const bf16x8*)(vin + base);
  float v[8];
#pragma unroll
  for (int j = 0; j < 8; ++j) v[j] = (float)inv[j];
  float s = 0.f, s2 = 0.f;
#pragma unroll
  for (int j = 0; j < 8; ++j) { s += v[j]; s2 += v[j] * v[j]; }
#pragma unroll
  for (int d = 1; d < 64; d <<= 1) { s += __shfl_xor(s, d); s2 += __shfl_xor(s2, d); }
  float mean = s * (1.f / 512.f);
  float var = s2 * (1.f / 512.f) - mean * mean;
  float rstd = rsqrtf(var + 1e-5f);

  bf16x8 r8 = *(const bf16x8*)(res + base);
  f32x4 g1 = *(const f32x4*)(gam + lane * 8);
  f32x4 g2 = *(const f32x4*)(gam + lane * 8 + 4);
  f32x4 b1 = *(const f32x4*)(bet + lane * 8);
  f32x4 b2 = *(const f32x4*)(bet + lane * 8 + 4);

  bf16x8 ob;
  f32x4 o1, o2;
#pragma unroll
  for (int j = 0; j < 8; ++j) {
    float g = (j < 4) ? g1[j] : g2[j - 4];
    float b = (j < 4) ? b1[j] : b2[j - 4];
    float ln = (v[j] - mean) * rstd * g + b;
    float ov = (float)r8[j] + ln;
    if (MODE == 0) ob[j] = (bf16)ov;
    else { if (j < 4) o1[j] = ov; else o2[j - 4] = ov; }
  }
  if (MODE == 0) *(bf16x8*)(outb + base) = ob;
  else { *(f32x4*)(outf + base) = o1; *(f32x4*)(outf + base + 4) = o2; }
}

// ---------------- launch
extern "C" void kernel_launch(void* const* d_in, const int* in_sizes, int n_in,
                              void* d_out, int out_size, void* d_ws, size_t ws_size,
                              hipStream_t stream) {
  const float* x    = (const float*)d_in[0];
  const float* n1g  = (const float*)d_in[3];
  const float* n1b  = (const float*)d_in[4];
  const float* qkvw = (const float*)d_in[5];
  const float* qb   = (const float*)d_in[6];
  const float* vb   = (const float*)d_in[7];
  const float* lsc  = (const float*)d_in[8];
  const float* cw1  = (const float*)d_in[9];
  const float* cb1  = (const float*)d_in[10];
  const float* cw2  = (const float*)d_in[11];
  const float* pw   = (const float*)d_in[12];
  const float* pb   = (const float*)d_in[13];
  const float* n2g  = (const float*)d_in[14];
  const float* n2b  = (const float*)d_in[15];
  const float* f1w  = (const float*)d_in[16];
  const float* f1b  = (const float*)d_in[17];
  const float* f2w  = (const float*)d_in[18];
  const float* f2b  = (const float*)d_in[19];

  // workspace layout (bytes), peak 75,563,008 (proven rounds 4-7):
  //   weights/bias @0..8,454,144 (as before)
  //   xb    @8,454,144  (16.8M) [start -> LN1];  h1 reuses @8,454,144 (33.55M,
  //         FC1 -> FC2, ends exactly at 42,008,576)
  //   qkv_t @25,231,360 (50.3M) [QKV -> attn];  projo reuses @25,231,360 (16.8M)
  //   x1b   @42,008,576 (16.8M) [LN1 -> final]
  //   m_buf @58,785,792 (16.8M) [FC2 -> final]
  // d_out: attn_o (16.8M), then h0 (33.5M), then final f32 out.
  char* ws = (char*)d_ws;
  bf16*  qkvw_b = (bf16*)(ws);
  bf16*  pw_b   = (bf16*)(ws + 1572864);
  bf16*  f1w_b  = (bf16*)(ws + 2097152);
  bf16*  f2w_b  = (bf16*)(ws + 4194304);
  float* btab   = (float*)(ws + 6291456);
  bf16*  bias_m = (bf16*)(ws + 6356992);
  bf16*  xb     = (bf16*)(ws + 8454144);
  bf16*  h1     = (bf16*)(ws + 8454144);
  bf16*  qkv_t  = (bf16*)(ws + 25231360);
  bf16*  projo  = (bf16*)(ws + 25231360);
  bf16*  x1b    = (bf16*)(ws + 42008576);
  bf16*  m_buf  = (bf16*)(ws + 58785792);
  bf16*  attn_o = (bf16*)d_out;
  bf16*  h0     = (bf16*)d_out;

  f2b_k<<<4096, 256, 0, stream>>>(x, xb, 1048576);
  f2b_k<<<384,  256, 0, stream>>>(qkvw, qkvw_b, 98304);
  f2b_k<<<128,  256, 0, stream>>>(pw, pw_b, 32768);
  f2b_k<<<512,  256, 0, stream>>>(f1w, f1w_b, 131072);
  f2b_k<<<512,  256, 0, stream>>>(f2w, f2w_b, 131072);
  cpb_tbl_k<<<961, 64, 0, stream>>>(cw1, cb1, cw2, btab);
  bias_exp_k<<<512, 256, 0, stream>>>(btab, bias_m);

  gemm2_k<0><<<dim3(128, 12), 512, 0, stream>>>(xb, nullptr, qkvw_b, qb, vb, qkv_t, nullptr, 512, 512, 512, 1536);
  attn_k<<<dim3(16, 64), 256, 0, stream>>>(qkv_t, bias_m, lsc, attn_o);
  gemm2_k<1><<<dim3(128, 4), 512, 0, stream>>>(attn_o, nullptr, pw_b, pb, nullptr, projo, nullptr, 512, 512, 512, 512);
  ln_res_k<0><<<4096, 256, 0, stream>>>(projo, xb, n1g, n1b, x1b, nullptr);
  gemm2_k<2><<<dim3(128, 16), 512, 0, stream>>>(x1b, nullptr, f1w_b, f1b, nullptr, h0, h1, 512, 512, 512, 1024);
  gemm2_k<3><<<dim3(128, 4), 512, 0, stream>>>(h0, h1, f2w_b, f2b, nullptr, m_buf, nullptr, 2048, 1024, 2048, 512);
  ln_res_k<1><<<4096, 256, 0, stream>>>(m_buf, x1b, n2g, n2b, nullptr, (float*)d_out);
}

// Round 9
// 232.765 us; speedup vs baseline: 1.7515x; 1.0561x over previous
//
#include <hip/hip_runtime.h>

typedef __bf16 bf16;
typedef __bf16 bf16x8 __attribute__((ext_vector_type(8)));
typedef float  f32x4  __attribute__((ext_vector_type(4)));

#define MFMA(a, b, c) __builtin_amdgcn_mfma_f32_16x16x32_bf16((a), (b), (c), 0, 0, 0)
#define LOG2E 1.4426950408889634f

__device__ __forceinline__ void gload16(const bf16* g, bf16* l) {
  __builtin_amdgcn_global_load_lds(
      (const __attribute__((address_space(1))) unsigned int*)g,
      (__attribute__((address_space(3))) unsigned int*)l, 16, 0, 0);
}

// fast GELU: x * e/(e+1), e = exp2(2*log2e*(0.79788456x + 0.0356774x^3))
// (tanh formulation; clamped where tanh==1; max |err| vs exact ~3e-3, sub-bf16-ulp)
__device__ __forceinline__ float gelu_f(float v) {
  float u = v * (0.7978845608f + 0.0356774081f * v * v);
  float t2 = fminf(u * (2.f * LOG2E), 126.f);
  float e = __builtin_amdgcn_exp2f(t2);
  return v * e * __builtin_amdgcn_rcpf(e + 1.f);
}

// ---------------- f32 -> bf16 bulk convert (8 elems/thread)
__global__ __launch_bounds__(256)
void f2b_k(const float* __restrict__ in, bf16* __restrict__ out, int n8)
{
  int i = blockIdx.x * 256 + threadIdx.x;
  if (i >= n8) return;
  f32x4 a = *(const f32x4*)(in + (size_t)i * 8);
  f32x4 b = *(const f32x4*)(in + (size_t)i * 8 + 4);
  bf16x8 o;
#pragma unroll
  for (int j = 0; j < 4; ++j) { o[j] = (bf16)a[j]; o[4 + j] = (bf16)b[j]; }
  *(bf16x8*)(out + (size_t)i * 8) = o;
}

// shifted-window token t = w*256+n  ->  natural token index (b*4096 + gh*64 + gw)
__device__ __forceinline__ int row_map(int t) {
  int w = t >> 8, n = t & 255;
  int b = w >> 4, wi = w & 15;
  int gh = (((wi >> 2) << 4) + (n >> 4) + 8) & 63;
  int gw = (((wi & 3) << 4) + (n & 15) + 8) & 63;
  return (b << 12) + (gh << 6) + gw;
}

// ---------------- GEMM v2: 128x128 tile, BK=64, 512 thr (8 waves 2Mx4N),
// counted-vmcnt two-barrier K-loop (loads stay in flight); XOR-swizzled LDS.
// MODE 0: QKV  (A row-gather via row_map, bias=concat(qb,0,vb))
// MODE 1: PROJ (bias, out rows scattered via row_map)
// MODE 2: FC1  (bias + fast GELU, out split h0/h1 by column half)
// MODE 3: FC2  (bias, A split h0/h1 by k half, K=2048)
template<int MODE>
__global__ __launch_bounds__(512)
void gemm2_k(const bf16* __restrict__ A0, const bf16* __restrict__ A1,
             const bf16* __restrict__ W,
             const float* __restrict__ b0, const float* __restrict__ b1,
             bf16* __restrict__ out0, bf16* __restrict__ out1,
             int K, int lda, int ldw, int ldc)
{
  __shared__ __align__(16) bf16 As[2][128 * 64];   // 32 KB
  __shared__ __align__(16) bf16 Bs[2][128 * 64];   // 32 KB
  const int tid  = threadIdx.x;
  const int lane = tid & 63;
  const int wave = tid >> 6;
  const int wm = wave >> 2, wn = wave & 3;         // 2 x 4 waves
  const int fr = lane & 15, fq = lane >> 4;
  const int m0 = blockIdx.x * 128, n0 = blockIdx.y * 128;

  f32x4 acc[4][2] = {};

  auto stage = [&](int buf, int t) {
    const int kb = t << 6;
#pragma unroll
    for (int i = 0; i < 2; ++i) {
      int c = tid + i * 512;                 // chunk 0..1023 (16B each)
      int row = c >> 3, sl = c & 7;
      int kk = ((sl ^ (row & 7)) << 3);      // swizzled source slot
      int arow = m0 + row;
      if (MODE == 0) arow = row_map(arow);
      const bf16* ap;
      if (MODE == 3) {
        const bf16* Ab = (kb < 1024) ? A0 : A1;
        ap = Ab + (size_t)arow * lda + (kb & 1023) + kk;
      } else {
        ap = A0 + (size_t)arow * lda + kb + kk;
      }
      gload16(ap, &As[buf][c * 8]);
      gload16(W + (size_t)(n0 + row) * ldw + kb + kk, &Bs[buf][c * 8]);
    }
  };

  const int nt = K >> 6;
  stage(0, 0);
  for (int t = 0; t < nt; ++t) {
    if (t + 1 < nt) {
      stage((t + 1) & 1, t + 1);                       // issue next tile first
      asm volatile("s_waitcnt vmcnt(4)" ::: "memory"); // tile t landed; t+1 flying
    } else {
      asm volatile("s_waitcnt vmcnt(0)" ::: "memory");
    }
    __builtin_amdgcn_s_barrier();                      // all waves' tile-t data in LDS
    const bf16* as = As[t & 1];
    const bf16* bs = Bs[t & 1];
#pragma unroll
    for (int k2 = 0; k2 < 2; ++k2) {
      const int sw = ((k2 * 4 + fq) ^ (fr & 7)) << 3;
      bf16x8 bF[2];
#pragma unroll
      for (int n = 0; n < 2; ++n)
        bF[n] = *(const bf16x8*)&bs[(wn * 32 + n * 16 + fr) * 64 + sw];
#pragma unroll
      for (int m = 0; m < 4; ++m) {
        bf16x8 aF = *(const bf16x8*)&as[(wm * 64 + m * 16 + fr) * 64 + sw];
#pragma unroll
        for (int n = 0; n < 2; ++n)
          acc[m][n] = MFMA(aF, bF[n], acc[m][n]);
      }
    }
    __builtin_amdgcn_s_barrier();                      // readers done before overwrite
  }

#pragma unroll
  for (int m = 0; m < 4; ++m) {
#pragma unroll
    for (int n = 0; n < 2; ++n) {
      int colb = n0 + wn * 32 + n * 16 + fr;
      float badd;
      if (MODE == 0)
        badd = (colb < 512) ? b0[colb] : (colb < 1024 ? 0.f : b1[colb - 1024]);
      else
        badd = b0[colb];
#pragma unroll
      for (int r = 0; r < 4; ++r) {
        int rowb = m0 + wm * 64 + m * 16 + fq * 4 + r;
        float v = acc[m][n][r] + badd;
        if (MODE == 0) out0[(size_t)rowb * ldc + colb] = (bf16)v;
        if (MODE == 1) out0[(size_t)row_map(rowb) * ldc + colb] = (bf16)v;
        if (MODE == 2) {
          v = gelu_f(v);
          bf16* ob = (colb < 1024) ? out0 : out1;
          ob[(size_t)rowb * 1024 + (colb & 1023)] = (bf16)v;
        }
        if (MODE == 3) out0[(size_t)rowb * ldc + colb] = (bf16)v;
      }
    }
  }
}

// ---------------- CPB MLP: btab[q][16], q = (dr+15)*31 + (dc+15)
__device__ __forceinline__ float cpb_coord(int r) {
  float t = (float)r * (8.0f / 15.0f);
  float v = log2f(fabsf(t) + 1.0f) * (1.0f / 3.0f);
  return (t < 0.0f) ? -v : v;
}

__global__ __launch_bounds__(64)
void cpb_tbl_k(const float* __restrict__ w1, const float* __restrict__ b1,
               const float* __restrict__ w2, float* __restrict__ btab)
{
  const int q = blockIdx.x;           // 0..960
  const int lane = threadIdx.x;       // 64
  const float t0 = cpb_coord(q / 31 - 15);
  const float t1 = cpb_coord(q % 31 - 15);
  float part[16];
#pragma unroll
  for (int o = 0; o < 16; ++o) part[o] = 0.f;
  for (int jj = 0; jj < 8; ++jj) {
    int j = lane * 8 + jj;
    float hv = t0 * w1[j * 2] + t1 * w1[j * 2 + 1] + b1[j];
    hv = fmaxf(hv, 0.f);
#pragma unroll
    for (int o = 0; o < 16; ++o) part[o] += hv * w2[o * 512 + j];
  }
#pragma unroll
  for (int o = 0; o < 16; ++o) {
#pragma unroll
    for (int d = 1; d < 64; d <<= 1) part[o] += __shfl_xor(part[o], d);
  }
  if (lane == 0) {
#pragma unroll
    for (int o = 0; o < 16; ++o) btab[q * 16 + o] = part[o];
  }
}

// bias_m[h][fr][i][nthi] = (16*sigmoid(rpb[h][i][nthi*16+fr]) - 8) * LOG2E
__global__ __launch_bounds__(256)
void bias_exp_k(const float* __restrict__ btab, bf16* __restrict__ bias_m)
{
  int e = blockIdx.x * 256 + threadIdx.x;      // < 131072, 8 nthi per thread
  int h = e >> 13, rem = e & 8191;             // rem: fr(4) i(8) half(1)
  int fr = rem >> 9, i = (rem >> 1) & 255, half = rem & 1;
  bf16x8 o;
#pragma unroll
  for (int jj = 0; jj < 8; ++jj) {
    int nthi = half * 8 + jj;
    int q = ((i >> 4) - nthi + 15) * 31 + ((i & 15) - fr + 15);
    float v = (16.f / (1.f + __expf(-btab[q * 16 + h])) - 8.f) * LOG2E;
    o[jj] = (bf16)v;
  }
  *(bf16x8*)&bias_m[(size_t)e * 8] = o;
}

// ---------------- attention: block = (head hh, window w), 256 thr, 4 Q-chunks
// fixed-shift exp2 softmax; k in 2 halves of 128; LDS 51,968 B -> 3 blocks/CU.
#define KP 36
#define VP 260
#define PP 132
__global__ __launch_bounds__(256)
void attn_k(const bf16* __restrict__ qkv, const bf16* __restrict__ bias_m,
            const float* __restrict__ lsc, bf16* __restrict__ attn_out)
{
  const int hh = blockIdx.x;     // 0..15
  const int w  = blockIdx.y;     // 0..63
  const int tid = threadIdx.x, lane = tid & 63, wave = tid >> 6;
  const int fr = lane & 15, fq = lane >> 4;
  const int r0 = wave * 16;

  __shared__ __align__(16) bf16 Ks[256 * KP];
  __shared__ __align__(16) bf16 Vt[32 * VP];
  __shared__ __align__(16) bf16 Ps[64 * PP];

  const size_t base = (size_t)(w * 256) * 1536;
  const float sc2 = __expf(fminf(lsc[hh], 4.6051701859880914f)) * LOG2E;
  const float shift = sc2 + 12.0f;

#pragma unroll
  for (int i = 0; i < 4; ++i) {
    int c = tid + i * 256;
    int row = c >> 2, d = (c & 3) << 3;
    bf16x8 kv = *(const bf16x8*)&qkv[base + (size_t)row * 1536 + 512 + hh * 32 + d];
    float ss = 0.f;
#pragma unroll
    for (int j = 0; j < 8; ++j) { float f = (float)kv[j]; ss += f * f; }
    ss += __shfl_xor(ss, 1); ss += __shfl_xor(ss, 2);
    float fac = 1.f / fmaxf(sqrtf(ss), 1e-12f);
#pragma unroll
    for (int j = 0; j < 8; ++j) kv[j] = (bf16)((float)kv[j] * fac);
    *(bf16x8*)&Ks[row * KP + d] = kv;
    bf16x8 v = *(const bf16x8*)&qkv[base + (size_t)row * 1536 + 1024 + hh * 32 + d];
#pragma unroll
    for (int j = 0; j < 8; ++j) Vt[(d + j) * VP + row] = v[j];
  }
  __syncthreads();

  const bool vrow = ((w >> 2) & 3) == 3, vcol = (w & 3) == 3;
  const f32x4 zero = {0.f, 0.f, 0.f, 0.f};

  for (int cb = 0; cb < 4; ++cb) {
    bf16x8 aQ = *(const bf16x8*)&qkv[base + (size_t)(cb * 64 + r0 + fr) * 1536 + hh * 32 + fq * 8];
    {
      float ss = 0.f;
#pragma unroll
      for (int j = 0; j < 8; ++j) { float f = (float)aQ[j]; ss += f * f; }
      ss += __shfl_xor(ss, 16); ss += __shfl_xor(ss, 32);
      float fac = sc2 / fmaxf(sqrtf(ss), 1e-12f);
#pragma unroll
      for (int j = 0; j < 8; ++j) aQ[j] = (bf16)((float)aQ[j] * fac);
    }

    float rs[4] = {0.f, 0.f, 0.f, 0.f};
    f32x4 o[2] = {};

#pragma unroll
    for (int kh = 0; kh < 2; ++kh) {
      bf16x8 br[4];
      {
        const bf16* bp = bias_m +
            (size_t)(((hh * 16 + fr) * 256) + cb * 64 + r0 + fq * 4) * 16 + kh * 8;
#pragma unroll
        for (int rr = 0; rr < 4; ++rr) br[rr] = *(const bf16x8*)&bp[rr * 16];
      }

      f32x4 s[8];
#pragma unroll
      for (int nt = 0; nt < 8; ++nt) {
        bf16x8 bK = *(const bf16x8*)&Ks[((kh * 8 + nt) * 16 + fr) * KP + fq * 8];
        s[nt] = MFMA(aQ, bK, zero);
      }

#pragma unroll
      for (int r = 0; r < 4; ++r) {
        int ni = cb * 64 + r0 + fq * 4 + r;
        int ri = ni >> 4, ci = ni & 15;
        bool colm = vcol && ((ci < 8) != (fr < 8));
        bool rowm = vrow && ((ri < 8) != (kh == 0));
        float c = ((colm || rowm) ? -144.2695f : 0.f) - shift;
        float part = 0.f;
#pragma unroll
        for (int nt = 0; nt < 8; ++nt) {
          float p = __builtin_amdgcn_exp2f(s[nt][r] + (float)br[r][nt] + c);
          s[nt][r] = p;
          part += p;
        }
        rs[r] += part;
      }

#pragma unroll
      for (int nt = 0; nt < 8; ++nt)
#pragma unroll
        for (int r = 0; r < 4; ++r)
          Ps[(r0 + fq * 4 + r) * PP + nt * 16 + fr] = (bf16)s[nt][r];

#pragma unroll
      for (int ks = 0; ks < 4; ++ks) {
        bf16x8 aP = *(const bf16x8*)&Ps[(r0 + fr) * PP + ks * 32 + fq * 8];
#pragma unroll
        for (int n2 = 0; n2 < 2; ++n2) {
          bf16x8 bV = *(const bf16x8*)&Vt[(n2 * 16 + fr) * VP + kh * 128 + ks * 32 + fq * 8];
          o[n2] = MFMA(aP, bV, o[n2]);
        }
      }
    }

#pragma unroll
    for (int r = 0; r < 4; ++r) {
      float sum = rs[r];
      sum += __shfl_xor(sum, 1); sum += __shfl_xor(sum, 2);
      sum += __shfl_xor(sum, 4); sum += __shfl_xor(sum, 8);
      float inv = __builtin_amdgcn_rcpf(sum);
      int ni = cb * 64 + r0 + fq * 4 + r;
#pragma unroll
      for (int n2 = 0; n2 < 2; ++n2)
        attn_out[((size_t)(w * 256 + ni)) * 512 + hh * 32 + n2 * 16 + fr] =
            (bf16)(o[n2][r] * inv);
    }
  }
}

// ---------------- LayerNorm + residual: out = res(bf16) + LN(vin)
template<int MODE>
__global__ __launch_bounds__(256)
void ln_res_k(const bf16* __restrict__ vin, const bf16* __restrict__ res,
              const float* __restrict__ gam, const float* __restrict__ bet,
              bf16* __restrict__ outb, float* __restrict__ outf)
{
  const int row = blockIdx.x * 4 + (threadIdx.x >> 6);
  const int lane = threadIdx.x & 63;
  const size_t base = (size_t)row * 512 + lane * 8;
  bf16x8 inv = *(const bf16x8*)(vin + base);
  float v[8];
#pragma unroll
  for (int j = 0; j < 8; ++j) v[j] = (float)inv[j];
  float s = 0.f, s2 = 0.f;
#pragma unroll
  for (int j = 0; j < 8; ++j) { s += v[j]; s2 += v[j] * v[j]; }
#pragma unroll
  for (int d = 1; d < 64; d <<= 1) { s += __shfl_xor(s, d); s2 += __shfl_xor(s2, d); }
  float mean = s * (1.f / 512.f);
  float var = s2 * (1.f / 512.f) - mean * mean;
  float rstd = rsqrtf(var + 1e-5f);

  bf16x8 r8 = *(const bf16x8*)(res + base);
  f32x4 g1 = *(const f32x4*)(gam + lane * 8);
  f32x4 g2 = *(const f32x4*)(gam + lane * 8 + 4);
  f32x4 b1 = *(const f32x4*)(bet + lane * 8);
  f32x4 b2 = *(const f32x4*)(bet + lane * 8 + 4);

  bf16x8 ob;
  f32x4 o1, o2;
#pragma unroll
  for (int j = 0; j < 8; ++j) {
    float g = (j < 4) ? g1[j] : g2[j - 4];
    float b = (j < 4) ? b1[j] : b2[j - 4];
    float ln = (v[j] - mean) * rstd * g + b;
    float ov = (float)r8[j] + ln;
    if (MODE == 0) ob[j] = (bf16)ov;
    else { if (j < 4) o1[j] = ov; else o2[j - 4] = ov; }
  }
  if (MODE == 0) *(bf16x8*)(outb + base) = ob;
  else { *(f32x4*)(outf + base) = o1; *(f32x4*)(outf + base + 4) = o2; }
}

// ---------------- launch
extern "C" void kernel_launch(void* const* d_in, const int* in_sizes, int n_in,
                              void* d_out, int out_size, void* d_ws, size_t ws_size,
                              hipStream_t stream) {
  const float* x    = (const float*)d_in[0];
  const float* n1g  = (const float*)d_in[3];
  const float* n1b  = (const float*)d_in[4];
  const float* qkvw = (const float*)d_in[5];
  const float* qb   = (const float*)d_in[6];
  const float* vb   = (const float*)d_in[7];
  const float* lsc  = (const float*)d_in[8];
  const float* cw1  = (const float*)d_in[9];
  const float* cb1  = (const float*)d_in[10];
  const float* cw2  = (const float*)d_in[11];
  const float* pw   = (const float*)d_in[12];
  const float* pb   = (const float*)d_in[13];
  const float* n2g  = (const float*)d_in[14];
  const float* n2b  = (const float*)d_in[15];
  const float* f1w  = (const float*)d_in[16];
  const float* f1b  = (const float*)d_in[17];
  const float* f2w  = (const float*)d_in[18];
  const float* f2b  = (const float*)d_in[19];

  // workspace layout (bytes), peak 75,563,008 (proven rounds 4-8):
  //   weights/bias @0..8,454,144
  //   xb    @8,454,144  (16.8M) [start -> LN1];  h1 reuses @8,454,144 (33.55M)
  //   qkv_t @25,231,360 (50.3M) [QKV -> attn];  projo reuses (16.8M)
  //   x1b   @42,008,576 (16.8M) [LN1 -> final]
  //   m_buf @58,785,792 (16.8M) [FC2 -> final]
  // d_out: attn_o (16.8M), then h0 (33.5M), then final f32 out.
  char* ws = (char*)d_ws;
  bf16*  qkvw_b = (bf16*)(ws);
  bf16*  pw_b   = (bf16*)(ws + 1572864);
  bf16*  f1w_b  = (bf16*)(ws + 2097152);
  bf16*  f2w_b  = (bf16*)(ws + 4194304);
  float* btab   = (float*)(ws + 6291456);
  bf16*  bias_m = (bf16*)(ws + 6356992);
  bf16*  xb     = (bf16*)(ws + 8454144);
  bf16*  h1     = (bf16*)(ws + 8454144);
  bf16*  qkv_t  = (bf16*)(ws + 25231360);
  bf16*  projo  = (bf16*)(ws + 25231360);
  bf16*  x1b    = (bf16*)(ws + 42008576);
  bf16*  m_buf  = (bf16*)(ws + 58785792);
  bf16*  attn_o = (bf16*)d_out;
  bf16*  h0     = (bf16*)d_out;

  f2b_k<<<4096, 256, 0, stream>>>(x, xb, 1048576);
  f2b_k<<<384,  256, 0, stream>>>(qkvw, qkvw_b, 98304);
  f2b_k<<<128,  256, 0, stream>>>(pw, pw_b, 32768);
  f2b_k<<<512,  256, 0, stream>>>(f1w, f1w_b, 131072);
  f2b_k<<<512,  256, 0, stream>>>(f2w, f2w_b, 131072);
  cpb_tbl_k<<<961, 64, 0, stream>>>(cw1, cb1, cw2, btab);
  bias_exp_k<<<512, 256, 0, stream>>>(btab, bias_m);

  gemm2_k<0><<<dim3(128, 12), 512, 0, stream>>>(xb, nullptr, qkvw_b, qb, vb, qkv_t, nullptr, 512, 512, 512, 1536);
  attn_k<<<dim3(16, 64), 256, 0, stream>>>(qkv_t, bias_m, lsc, attn_o);
  gemm2_k<1><<<dim3(128, 4), 512, 0, stream>>>(attn_o, nullptr, pw_b, pb, nullptr, projo, nullptr, 512, 512, 512, 512);
  ln_res_k<0><<<4096, 256, 0, stream>>>(projo, xb, n1g, n1b, x1b, nullptr);
  gemm2_k<2><<<dim3(128, 16), 512, 0, stream>>>(x1b, nullptr, f1w_b, f1b, nullptr, h0, h1, 512, 512, 512, 1024);
  gemm2_k<3><<<dim3(128, 4), 512, 0, stream>>>(h0, h1, f2w_b, f2b, nullptr, m_buf, nullptr, 2048, 1024, 2048, 512);
  ln_res_k<1><<<4096, 256, 0, stream>>>(m_buf, x1b, n2g, n2b, nullptr, (float*)d_out);
}

// Round 10
// 228.054 us; speedup vs baseline: 1.7877x; 1.0207x over previous
//
#include <hip/hip_runtime.h>

typedef __bf16 bf16;
typedef __bf16 bf16x8 __attribute__((ext_vector_type(8)));
typedef float  f32x4  __attribute__((ext_vector_type(4)));

#define MFMA(a, b, c) __builtin_amdgcn_mfma_f32_16x16x32_bf16((a), (b), (c), 0, 0, 0)
#define LOG2E 1.4426950408889634f

__device__ __forceinline__ void gload16(const bf16* g, bf16* l) {
  __builtin_amdgcn_global_load_lds(
      (const __attribute__((address_space(1))) unsigned int*)g,
      (__attribute__((address_space(3))) unsigned int*)l, 16, 0, 0);
}

// fast GELU: x * e/(e+1), e = exp2(2*log2e*(0.79788456x + 0.0356774x^3))
__device__ __forceinline__ float gelu_f(float v) {
  float u = v * (0.7978845608f + 0.0356774081f * v * v);
  float t2 = fminf(u * (2.f * LOG2E), 126.f);
  float e = __builtin_amdgcn_exp2f(t2);
  return v * e * __builtin_amdgcn_rcpf(e + 1.f);
}

// ---------------- fused f32 -> bf16 convert for x + 4 weight tensors
__global__ __launch_bounds__(256)
void f2b_all_k(const float* __restrict__ x, const float* __restrict__ qkvw,
               const float* __restrict__ pw, const float* __restrict__ f1w,
               const float* __restrict__ f2w,
               bf16* __restrict__ xb, bf16* __restrict__ qkvwb,
               bf16* __restrict__ pwb, bf16* __restrict__ f1wb,
               bf16* __restrict__ f2wb)
{
  int i = blockIdx.x * 256 + threadIdx.x;   // 8-elem chunk index
  const float* in; bf16* out; int base;
  if      (i < 1048576) { in = x;    out = xb;    base = 0; }
  else if (i < 1146880) { in = qkvw; out = qkvwb; base = 1048576; }
  else if (i < 1179648) { in = pw;   out = pwb;   base = 1146880; }
  else if (i < 1310720) { in = f1w;  out = f1wb;  base = 1179648; }
  else if (i < 1441792) { in = f2w;  out = f2wb;  base = 1310720; }
  else return;
  size_t j = (size_t)(i - base) * 8;
  f32x4 a = *(const f32x4*)(in + j);
  f32x4 b = *(const f32x4*)(in + j + 4);
  bf16x8 o;
#pragma unroll
  for (int k = 0; k < 4; ++k) { o[k] = (bf16)a[k]; o[4 + k] = (bf16)b[k]; }
  *(bf16x8*)(out + j) = o;
}

// shifted-window token t = w*256+n  ->  natural token index (b*4096 + gh*64 + gw)
__device__ __forceinline__ int row_map(int t) {
  int w = t >> 8, n = t & 255;
  int b = w >> 4, wi = w & 15;
  int gh = (((wi >> 2) << 4) + (n >> 4) + 8) & 63;
  int gw = (((wi & 3) << 4) + (n & 15) + 8) & 63;
  return (b << 12) + (gh << 6) + gw;
}

// ---------------- GEMM v2: 128x128 tile, BK=64, 512 thr (8 waves 2Mx4N).
// T3-minimum loop: stage(t+1)->buf^1 at tile top, 2 interleaved sub-phases
// (ds_read || stage-in-flight || MFMA+setprio), ONE vmcnt(0)+barrier per tile.
// XOR-swizzled LDS (pre-swizzled global source, linear dest, swizzled read).
// MODE 0: QKV  (A row-gather via row_map, bias=concat(qb,0,vb))
// MODE 1: PROJ (bias, out rows scattered via row_map)
// MODE 2: FC1  (bias + fast GELU, out split h0/h1 by column half)
// MODE 3: FC2  (bias, A split h0/h1 by k half, K=2048)
template<int MODE>
__global__ __launch_bounds__(512)
void gemm2_k(const bf16* __restrict__ A0, const bf16* __restrict__ A1,
             const bf16* __restrict__ W,
             const float* __restrict__ b0, const float* __restrict__ b1,
             bf16* __restrict__ out0, bf16* __restrict__ out1,
             int K, int lda, int ldw, int ldc)
{
  __shared__ __align__(16) bf16 As[2][128 * 64];   // 32 KB
  __shared__ __align__(16) bf16 Bs[2][128 * 64];   // 32 KB
  const int tid  = threadIdx.x;
  const int lane = tid & 63;
  const int wave = tid >> 6;
  const int wm = wave >> 2, wn = wave & 3;         // 2 x 4 waves
  const int fr = lane & 15, fq = lane >> 4;
  const int m0 = blockIdx.x * 128, n0 = blockIdx.y * 128;

  f32x4 acc[4][2] = {};

  auto stage = [&](int buf, int t) {
    const int kb = t << 6;
#pragma unroll
    for (int i = 0; i < 2; ++i) {
      int c = tid + i * 512;                 // chunk 0..1023 (16B each)
      int row = c >> 3, sl = c & 7;
      int kk = ((sl ^ (row & 7)) << 3);      // swizzled source slot
      int arow = m0 + row;
      if (MODE == 0) arow = row_map(arow);
      const bf16* ap;
      if (MODE == 3) {
        const bf16* Ab = (kb < 1024) ? A0 : A1;
        ap = Ab + (size_t)arow * lda + (kb & 1023) + kk;
      } else {
        ap = A0 + (size_t)arow * lda + kb + kk;
      }
      gload16(ap, &As[buf][c * 8]);
      gload16(W + (size_t)(n0 + row) * ldw + kb + kk, &Bs[buf][c * 8]);
    }
  };

  const int nt = K >> 6;
  stage(0, 0);
  asm volatile("s_waitcnt vmcnt(0)" ::: "memory");
  __builtin_amdgcn_s_barrier();
  for (int t = 0; t < nt; ++t) {
    if (t + 1 < nt) stage((t + 1) & 1, t + 1);     // into OTHER buffer; flies all tile
    const bf16* as = As[t & 1];
    const bf16* bs = Bs[t & 1];
#pragma unroll
    for (int k2 = 0; k2 < 2; ++k2) {
      const int sw = ((k2 * 4 + fq) ^ (fr & 7)) << 3;
      bf16x8 bF[2];
#pragma unroll
      for (int n = 0; n < 2; ++n)
        bF[n] = *(const bf16x8*)&bs[(wn * 32 + n * 16 + fr) * 64 + sw];
      bf16x8 aF[4];
#pragma unroll
      for (int m = 0; m < 4; ++m)
        aF[m] = *(const bf16x8*)&as[(wm * 64 + m * 16 + fr) * 64 + sw];
      __builtin_amdgcn_s_setprio(1);
#pragma unroll
      for (int m = 0; m < 4; ++m)
#pragma unroll
        for (int n = 0; n < 2; ++n)
          acc[m][n] = MFMA(aF[m], bF[n], acc[m][n]);
      __builtin_amdgcn_s_setprio(0);
    }
    if (t + 1 < nt) {
      asm volatile("s_waitcnt vmcnt(0)" ::: "memory");  // t+1's 4 loads landed
      __builtin_amdgcn_s_barrier();                     // all waves: reads done, data in
    }
  }

#pragma unroll
  for (int m = 0; m < 4; ++m) {
#pragma unroll
    for (int n = 0; n < 2; ++n) {
      int colb = n0 + wn * 32 + n * 16 + fr;
      float badd;
      if (MODE == 0)
        badd = (colb < 512) ? b0[colb] : (colb < 1024 ? 0.f : b1[colb - 1024]);
      else
        badd = b0[colb];
#pragma unroll
      for (int r = 0; r < 4; ++r) {
        int rowb = m0 + wm * 64 + m * 16 + fq * 4 + r;
        float v = acc[m][n][r] + badd;
        if (MODE == 0) out0[(size_t)rowb * ldc + colb] = (bf16)v;
        if (MODE == 1) out0[(size_t)row_map(rowb) * ldc + colb] = (bf16)v;
        if (MODE == 2) {
          v = gelu_f(v);
          bf16* ob = (colb < 1024) ? out0 : out1;
          ob[(size_t)rowb * 1024 + (colb & 1023)] = (bf16)v;
        }
        if (MODE == 3) out0[(size_t)rowb * ldc + colb] = (bf16)v;
      }
    }
  }
}

// ---------------- CPB MLP: btab[q][16], q = (dr+15)*31 + (dc+15)
__device__ __forceinline__ float cpb_coord(int r) {
  float t = (float)r * (8.0f / 15.0f);
  float v = log2f(fabsf(t) + 1.0f) * (1.0f / 3.0f);
  return (t < 0.0f) ? -v : v;
}

__global__ __launch_bounds__(64)
void cpb_tbl_k(const float* __restrict__ w1, const float* __restrict__ b1,
               const float* __restrict__ w2, float* __restrict__ btab)
{
  const int q = blockIdx.x;           // 0..960
  const int lane = threadIdx.x;       // 64
  const float t0 = cpb_coord(q / 31 - 15);
  const float t1 = cpb_coord(q % 31 - 15);
  float part[16];
#pragma unroll
  for (int o = 0; o < 16; ++o) part[o] = 0.f;
  for (int jj = 0; jj < 8; ++jj) {
    int j = lane * 8 + jj;
    float hv = t0 * w1[j * 2] + t1 * w1[j * 2 + 1] + b1[j];
    hv = fmaxf(hv, 0.f);
#pragma unroll
    for (int o = 0; o < 16; ++o) part[o] += hv * w2[o * 512 + j];
  }
#pragma unroll
  for (int o = 0; o < 16; ++o) {
#pragma unroll
    for (int d = 1; d < 64; d <<= 1) part[o] += __shfl_xor(part[o], d);
  }
  if (lane == 0) {
#pragma unroll
    for (int o = 0; o < 16; ++o) btab[q * 16 + o] = part[o];
  }
}

// bias_m[h][fr][i][nthi] = (16*sigmoid(rpb[h][i][nthi*16+fr]) - 8) * LOG2E
__global__ __launch_bounds__(256)
void bias_exp_k(const float* __restrict__ btab, bf16* __restrict__ bias_m)
{
  int e = blockIdx.x * 256 + threadIdx.x;      // < 131072, 8 nthi per thread
  int h = e >> 13, rem = e & 8191;             // rem: fr(4) i(8) half(1)
  int fr = rem >> 9, i = (rem >> 1) & 255, half = rem & 1;
  bf16x8 o;
#pragma unroll
  for (int jj = 0; jj < 8; ++jj) {
    int nthi = half * 8 + jj;
    int q = ((i >> 4) - nthi + 15) * 31 + ((i & 15) - fr + 15);
    float v = (16.f / (1.f + __expf(-btab[q * 16 + h])) - 8.f) * LOG2E;
    o[jj] = (bf16)v;
  }
  *(bf16x8*)&bias_m[(size_t)e * 8] = o;
}

// ---------------- attention: block = (head hh, window w), 256 thr, 4 Q-chunks
// fixed-shift exp2 softmax; k in 2 halves of 128; LDS 51,968 B -> 3 blocks/CU.
#define KP 36
#define VP 260
#define PP 132
__global__ __launch_bounds__(256)
void attn_k(const bf16* __restrict__ qkv, const bf16* __restrict__ bias_m,
            const float* __restrict__ lsc, bf16* __restrict__ attn_out)
{
  const int hh = blockIdx.x;     // 0..15
  const int w  = blockIdx.y;     // 0..63
  const int tid = threadIdx.x, lane = tid & 63, wave = tid >> 6;
  const int fr = lane & 15, fq = lane >> 4;
  const int r0 = wave * 16;

  __shared__ __align__(16) bf16 Ks[256 * KP];
  __shared__ __align__(16) bf16 Vt[32 * VP];
  __shared__ __align__(16) bf16 Ps[64 * PP];

  const size_t base = (size_t)(w * 256) * 1536;
  const float sc2 = __expf(fminf(lsc[hh], 4.6051701859880914f)) * LOG2E;
  const float shift = sc2 + 12.0f;

#pragma unroll
  for (int i = 0; i < 4; ++i) {
    int c = tid + i * 256;
    int row = c >> 2, d = (c & 3) << 3;
    bf16x8 kv = *(const bf16x8*)&qkv[base + (size_t)row * 1536 + 512 + hh * 32 + d];
    float ss = 0.f;
#pragma unroll
    for (int j = 0; j < 8; ++j) { float f = (float)kv[j]; ss += f * f; }
    ss += __shfl_xor(ss, 1); ss += __shfl_xor(ss, 2);
    float fac = 1.f / fmaxf(sqrtf(ss), 1e-12f);
#pragma unroll
    for (int j = 0; j < 8; ++j) kv[j] = (bf16)((float)kv[j] * fac);
    *(bf16x8*)&Ks[row * KP + d] = kv;
    bf16x8 v = *(const bf16x8*)&qkv[base + (size_t)row * 1536 + 1024 + hh * 32 + d];
#pragma unroll
    for (int j = 0; j < 8; ++j) Vt[(d + j) * VP + row] = v[j];
  }
  __syncthreads();

  const bool vrow = ((w >> 2) & 3) == 3, vcol = (w & 3) == 3;
  const f32x4 zero = {0.f, 0.f, 0.f, 0.f};

  for (int cb = 0; cb < 4; ++cb) {
    bf16x8 aQ = *(const bf16x8*)&qkv[base + (size_t)(cb * 64 + r0 + fr) * 1536 + hh * 32 + fq * 8];
    {
      float ss = 0.f;
#pragma unroll
      for (int j = 0; j < 8; ++j) { float f = (float)aQ[j]; ss += f * f; }
      ss += __shfl_xor(ss, 16); ss += __shfl_xor(ss, 32);
      float fac = sc2 / fmaxf(sqrtf(ss), 1e-12f);
#pragma unroll
      for (int j = 0; j < 8; ++j) aQ[j] = (bf16)((float)aQ[j] * fac);
    }

    float rs[4] = {0.f, 0.f, 0.f, 0.f};
    f32x4 o[2] = {};

#pragma unroll
    for (int kh = 0; kh < 2; ++kh) {
      bf16x8 br[4];
      {
        const bf16* bp = bias_m +
            (size_t)(((hh * 16 + fr) * 256) + cb * 64 + r0 + fq * 4) * 16 + kh * 8;
#pragma unroll
        for (int rr = 0; rr < 4; ++rr) br[rr] = *(const bf16x8*)&bp[rr * 16];
      }

      f32x4 s[8];
#pragma unroll
      for (int nt = 0; nt < 8; ++nt) {
        bf16x8 bK = *(const bf16x8*)&Ks[((kh * 8 + nt) * 16 + fr) * KP + fq * 8];
        s[nt] = MFMA(aQ, bK, zero);
      }

#pragma unroll
      for (int r = 0; r < 4; ++r) {
        int ni = cb * 64 + r0 + fq * 4 + r;
        int ri = ni >> 4, ci = ni & 15;
        bool colm = vcol && ((ci < 8) != (fr < 8));
        bool rowm = vrow && ((ri < 8) != (kh == 0));
        float c = ((colm || rowm) ? -144.2695f : 0.f) - shift;
        float part = 0.f;
#pragma unroll
        for (int nt = 0; nt < 8; ++nt) {
          float p = __builtin_amdgcn_exp2f(s[nt][r] + (float)br[r][nt] + c);
          s[nt][r] = p;
          part += p;
        }
        rs[r] += part;
      }

#pragma unroll
      for (int nt = 0; nt < 8; ++nt)
#pragma unroll
        for (int r = 0; r < 4; ++r)
          Ps[(r0 + fq * 4 + r) * PP + nt * 16 + fr] = (bf16)s[nt][r];

#pragma unroll
      for (int ks = 0; ks < 4; ++ks) {
        bf16x8 aP = *(const bf16x8*)&Ps[(r0 + fr) * PP + ks * 32 + fq * 8];
#pragma unroll
        for (int n2 = 0; n2 < 2; ++n2) {
          bf16x8 bV = *(const bf16x8*)&Vt[(n2 * 16 + fr) * VP + kh * 128 + ks * 32 + fq * 8];
          o[n2] = MFMA(aP, bV, o[n2]);
        }
      }
    }

#pragma unroll
    for (int r = 0; r < 4; ++r) {
      float sum = rs[r];
      sum += __shfl_xor(sum, 1); sum += __shfl_xor(sum, 2);
      sum += __shfl_xor(sum, 4); sum += __shfl_xor(sum, 8);
      float inv = __builtin_amdgcn_rcpf(sum);
      int ni = cb * 64 + r0 + fq * 4 + r;
#pragma unroll
      for (int n2 = 0; n2 < 2; ++n2)
        attn_out[((size_t)(w * 256 + ni)) * 512 + hh * 32 + n2 * 16 + fr] =
            (bf16)(o[n2][r] * inv);
    }
  }
}

// ---------------- LayerNorm + residual: out = res(bf16) + LN(vin)
template<int MODE>
__global__ __launch_bounds__(256)
void ln_res_k(const bf16* __restrict__ vin, const bf16* __restrict__ res,
              const float* __restrict__ gam, const float* __restrict__ bet,
              bf16* __restrict__ outb, float* __restrict__ outf)
{
  const int row = blockIdx.x * 4 + (threadIdx.x >> 6);
  const int lane = threadIdx.x & 63;
  const size_t base = (size_t)row * 512 + lane * 8;
  bf16x8 inv = *(const bf16x8*)(vin + base);
  float v[8];
#pragma unroll
  for (int j = 0; j < 8; ++j) v[j] = (float)inv[j];
  float s = 0.f, s2 = 0.f;
#pragma unroll
  for (int j = 0; j < 8; ++j) { s += v[j]; s2 += v[j] * v[j]; }
#pragma unroll
  for (int d = 1; d < 64; d <<= 1) { s += __shfl_xor(s, d); s2 += __shfl_xor(s2, d); }
  float mean = s * (1.f / 512.f);
  float var = s2 * (1.f / 512.f) - mean * mean;
  float rstd = rsqrtf(var + 1e-5f);

  bf16x8 r8 = *(const bf16x8*)(res + base);
  f32x4 g1 = *(const f32x4*)(gam + lane * 8);
  f32x4 g2 = *(const f32x4*)(gam + lane * 8 + 4);
  f32x4 b1 = *(const f32x4*)(bet + lane * 8);
  f32x4 b2 = *(const f32x4*)(bet + lane * 8 + 4);

  bf16x8 ob;
  f32x4 o1, o2;
#pragma unroll
  for (int j = 0; j < 8; ++j) {
    float g = (j < 4) ? g1[j] : g2[j - 4];
    float b = (j < 4) ? b1[j] : b2[j - 4];
    float ln = (v[j] - mean) * rstd * g + b;
    float ov = (float)r8[j] + ln;
    if (MODE == 0) ob[j] = (bf16)ov;
    else { if (j < 4) o1[j] = ov; else o2[j - 4] = ov; }
  }
  if (MODE == 0) *(bf16x8*)(outb + base) = ob;
  else { *(f32x4*)(outf + base) = o1; *(f32x4*)(outf + base + 4) = o2; }
}

// ---------------- launch
extern "C" void kernel_launch(void* const* d_in, const int* in_sizes, int n_in,
                              void* d_out, int out_size, void* d_ws, size_t ws_size,
                              hipStream_t stream) {
  const float* x    = (const float*)d_in[0];
  const float* n1g  = (const float*)d_in[3];
  const float* n1b  = (const float*)d_in[4];
  const float* qkvw = (const float*)d_in[5];
  const float* qb   = (const float*)d_in[6];
  const float* vb   = (const float*)d_in[7];
  const float* lsc  = (const float*)d_in[8];
  const float* cw1  = (const float*)d_in[9];
  const float* cb1  = (const float*)d_in[10];
  const float* cw2  = (const float*)d_in[11];
  const float* pw   = (const float*)d_in[12];
  const float* pb   = (const float*)d_in[13];
  const float* n2g  = (const float*)d_in[14];
  const float* n2b  = (const float*)d_in[15];
  const float* f1w  = (const float*)d_in[16];
  const float* f1b  = (const float*)d_in[17];
  const float* f2w  = (const float*)d_in[18];
  const float* f2b  = (const float*)d_in[19];

  // workspace layout (bytes), peak 75,563,008 (proven rounds 4-9):
  //   weights/bias @0..8,454,144
  //   xb    @8,454,144  (16.8M) [start -> LN1];  h1 reuses @8,454,144 (33.55M)
  //   qkv_t @25,231,360 (50.3M) [QKV -> attn];  projo reuses (16.8M)
  //   x1b   @42,008,576 (16.8M) [LN1 -> final]
  //   m_buf @58,785,792 (16.8M) [FC2 -> final]
  // d_out: attn_o (16.8M), then h0 (33.5M), then final f32 out.
  char* ws = (char*)d_ws;
  bf16*  qkvw_b = (bf16*)(ws);
  bf16*  pw_b   = (bf16*)(ws + 1572864);
  bf16*  f1w_b  = (bf16*)(ws + 2097152);
  bf16*  f2w_b  = (bf16*)(ws + 4194304);
  float* btab   = (float*)(ws + 6291456);
  bf16*  bias_m = (bf16*)(ws + 6356992);
  bf16*  xb     = (bf16*)(ws + 8454144);
  bf16*  h1     = (bf16*)(ws + 8454144);
  bf16*  qkv_t  = (bf16*)(ws + 25231360);
  bf16*  projo  = (bf16*)(ws + 25231360);
  bf16*  x1b    = (bf16*)(ws + 42008576);
  bf16*  m_buf  = (bf16*)(ws + 58785792);
  bf16*  attn_o = (bf16*)d_out;
  bf16*  h0     = (bf16*)d_out;

  f2b_all_k<<<5632, 256, 0, stream>>>(x, qkvw, pw, f1w, f2w,
                                      xb, qkvw_b, pw_b, f1w_b, f2w_b);
  cpb_tbl_k<<<961, 64, 0, stream>>>(cw1, cb1, cw2, btab);
  bias_exp_k<<<512, 256, 0, stream>>>(btab, bias_m);

  gemm2_k<0><<<dim3(128, 12), 512, 0, stream>>>(xb, nullptr, qkvw_b, qb, vb, qkv_t, nullptr, 512, 512, 512, 1536);
  attn_k<<<dim3(16, 64), 256, 0, stream>>>(qkv_t, bias_m, lsc, attn_o);
  gemm2_k<1><<<dim3(128, 4), 512, 0, stream>>>(attn_o, nullptr, pw_b, pb, nullptr, projo, nullptr, 512, 512, 512, 512);
  ln_res_k<0><<<4096, 256, 0, stream>>>(projo, xb, n1g, n1b, x1b, nullptr);
  gemm2_k<2><<<dim3(128, 16), 512, 0, stream>>>(x1b, nullptr, f1w_b, f1b, nullptr, h0, h1, 512, 512, 512, 1024);
  gemm2_k<3><<<dim3(128, 4), 512, 0, stream>>>(h0, h1, f2w_b, f2b, nullptr, m_buf, nullptr, 2048, 1024, 2048, 512);
  ln_res_k<1><<<4096, 256, 0, stream>>>(m_buf, x1b, n2g, n2b, nullptr, (float*)d_out);
}